// Round 5
// baseline (698.961 us; speedup 1.0000x reference)
//
#include <hip/hip_runtime.h>
#include <hip/hip_bf16.h>
#include <hip/hip_fp16.h>

// GCN: h = relu(GCN(x,W1,b1)); h = relu(GCN(h,W2,b2)); out = h @ Wfc + bfc
// GCN(x,W,b)[d] = dis[d] * ( sum_{(s,d) in E} hs[s] + hs[d] ) + b
//   where hs[v] = (x[v]@W) * dis[v],  dis[v] = rsqrt(1 + indeg(v))
//
// Round-19: preprocessing rebuilt as a direct per-node CSR (the bucket
// sort in k_hist/k_binscatter/k_csr only existed to derive rowptr/deg;
// aggregation is order-independent).  New pipeline: memset(deg) -> k_deg
// (global atomic histogram, int4 reads; block 0 also writes W2^T) ->
// gscan (emits rowptr + cursor copy + dis) -> k_scatter (per-node atomic
// cursors, writes plain src).  Saves k_csr's 25.6 MB rd+wr pass, the
// 800 KB ghist traffic, and 2 dispatches.  k_agg12 now loads its W2
// column from W2^T: 8 contiguous dwordx4 per wave instead of 32 scalar
// loads.  ents entries are plain src (no shift/mask in hot loops).
// Aggregation kernels keep the round-18 shape (one node/wave, fma_mix).

#define SCAN_CHUNK 1024

__device__ inline void f4fma(float4& a, float s, const float4& b) {
    a.x = fmaf(s, b.x, a.x); a.y = fmaf(s, b.y, a.y);
    a.z = fmaf(s, b.z, a.z); a.w = fmaf(s, b.w, a.w);
}
__device__ inline void f4add(float4& a, const float4& b) {
    a.x += b.x; a.y += b.y; a.z += b.z; a.w += b.w;
}
__device__ inline void f4red(float4& a, int off) {
    a.x += __shfl_xor(a.x, off); a.y += __shfl_xor(a.y, off);
    a.z += __shfl_xor(a.z, off); a.w += __shfl_xor(a.w, off);
}
// 8 halves (16 B) -> two float4 (single dwordx4 load)
__device__ inline void h8load(const __half* p, float4& a, float4& b) {
    uint4 r = *(const uint4*)p;
    __half2* h = (__half2*)&r;
    float2 f0 = __half22float2(h[0]);
    float2 f1 = __half22float2(h[1]);
    float2 f2 = __half22float2(h[2]);
    float2 f3 = __half22float2(h[3]);
    a = make_float4(f0.x, f0.y, f1.x, f1.y);
    b = make_float4(f2.x, f2.y, f3.x, f3.y);
}
// acc two packed halves into two f32 accumulators: one v_fma_mix each.
// fma(cvt_f32(h), 1.0f, acc) -- exact convert, single-rounded fma ==
// bit-identical to cvt+add.
__device__ inline void hacc2(unsigned h, float& x, float& y) {
    asm("v_fma_mix_f32 %0, %2, %3, %0 op_sel:[0,0,0] op_sel_hi:[1,0,0]\n\t"
        "v_fma_mix_f32 %1, %2, %3, %1 op_sel:[1,0,0] op_sel_hi:[1,0,0]"
        : "+v"(x), "+v"(y)
        : "v"(h), "v"(1.0f));
}
// 8 halves (one dwordx4) accumulated into the 8 f32 lanes of a,b
__device__ inline void h8acc(const __half* p, float4& a, float4& b) {
    uint4 r = *(const uint4*)p;
    hacc2(r.x, a.x, a.y);
    hacc2(r.y, a.z, a.w);
    hacc2(r.z, b.x, b.y);
    hacc2(r.w, b.z, b.w);
}
__device__ inline void h4store(__half* p, float4 v) {
    __half2 a = __floats2half2_rn(v.x, v.y);
    __half2 b = __floats2half2_rn(v.z, v.w);
    uint2 r; r.x = *(uint*)&a; r.y = *(uint*)&b;
    *(uint2*)p = r;
}

// ---- deg histogram (global atomics) + W2^T prep in block 0 ----
__global__ __launch_bounds__(256) void k_deg(const int* __restrict__ dst,
                                             int* __restrict__ deg,
                                             const float* __restrict__ W2,
                                             float* __restrict__ W2T, int e) {
    int tid = blockIdx.x * 256 + threadIdx.x;
    int i = tid * 4;
    int stride = gridDim.x * 1024;
    for (; i + 3 < e; i += stride) {
        int4 d4 = *(const int4*)&dst[i];
        atomicAdd(&deg[d4.x], 1);
        atomicAdd(&deg[d4.y], 1);
        atomicAdd(&deg[d4.z], 1);
        atomicAdd(&deg[d4.w], 1);
    }
    for (int u = (e & ~3) + tid; u < e; u += gridDim.x * 256)
        atomicAdd(&deg[dst[u]], 1);
    if (blockIdx.x == 0) {
        // W2T[c][k] = W2[k][c]  (32x64 f32, 8 KB)
        for (int j = threadIdx.x; j < 2048; j += 256)
            W2T[j] = W2[(j & 63) * 32 + (j >> 6)];
    }
}

// ---- exclusive scan of deg (m ints, nblk = ceil(m/1024) <= 256) ----
__global__ void k_gscan1(const int* __restrict__ in, int* __restrict__ part, int m) {
    int t = threadIdx.x;
    int base = blockIdx.x * SCAN_CHUNK + t * 4;
    int s = 0;
    for (int u = 0; u < 4; ++u) { int i = base + u; if (i < m) s += in[i]; }
    for (int o = 32; o; o >>= 1) s += __shfl_down(s, o);
    __shared__ int ws[4];
    if ((t & 63) == 0) ws[t >> 6] = s;
    __syncthreads();
    if (t == 0) part[blockIdx.x] = ws[0] + ws[1] + ws[2] + ws[3];
}

// also emits the scatter cursor copy and dis = rsqrt(deg+1)
__global__ void k_gscan2(const int* __restrict__ in, const int* __restrict__ part,
                         int* __restrict__ rowptr, int* __restrict__ cur,
                         float* __restrict__ dis, int m, int nblk) {
    int t = threadIdx.x;
    int b = blockIdx.x;
    int pv = (t < b && t < nblk) ? part[t] : 0;
    int ps = pv;
    for (int o = 32; o; o >>= 1) ps += __shfl_down(ps, o);
    __shared__ int sh[4];
    if ((t & 63) == 0) sh[t >> 6] = ps;
    __syncthreads();
    int blockoff = sh[0] + sh[1] + sh[2] + sh[3];

    int base = b * SCAN_CHUNK + t * 4;
    int v0 = 0, v1 = 0, v2 = 0, v3 = 0;
    if (base + 0 < m) v0 = in[base + 0];
    if (base + 1 < m) v1 = in[base + 1];
    if (base + 2 < m) v2 = in[base + 2];
    if (base + 3 < m) v3 = in[base + 3];
    int tot = v0 + v1 + v2 + v3;
    int lane = t & 63, wid = t >> 6;
    int incl = tot;
    for (int o = 1; o < 64; o <<= 1) { int u = __shfl_up(incl, o); if (lane >= o) incl += u; }
    int excl = incl - tot;
    __shared__ int wt[4];
    if (lane == 63) wt[wid] = incl;
    __syncthreads();
    int woff = 0;
    for (int w = 0; w < wid; ++w) woff += wt[w];
    int off = blockoff + woff + excl;
    if (base + 0 < m) { rowptr[base+0] = off;          cur[base+0] = off;          dis[base+0] = rsqrtf((float)(v0+1)); }
    if (base + 1 < m) { int o1 = off+v0;               rowptr[base+1] = o1; cur[base+1] = o1; dis[base+1] = rsqrtf((float)(v1+1)); }
    if (base + 2 < m) { int o2 = off+v0+v1;            rowptr[base+2] = o2; cur[base+2] = o2; dis[base+2] = rsqrtf((float)(v2+1)); }
    if (base + 3 < m) { int o3 = off+v0+v1+v2;         rowptr[base+3] = o3; cur[base+3] = o3; dis[base+3] = rsqrtf((float)(v3+1)); }
}

// ---- scatter edges to CSR positions (per-node atomic cursors) ----
__global__ __launch_bounds__(256) void k_scatter(
        const int* __restrict__ src, const int* __restrict__ dst,
        int* __restrict__ cur, int* __restrict__ ents, int e) {
    int tid = blockIdx.x * 256 + threadIdx.x;
    int i = tid * 4;
    int stride = gridDim.x * 1024;
    for (; i + 3 < e; i += stride) {
        int4 s4 = *(const int4*)&src[i];
        int4 d4 = *(const int4*)&dst[i];
        ents[atomicAdd(&cur[d4.x], 1)] = s4.x;
        ents[atomicAdd(&cur[d4.y], 1)] = s4.y;
        ents[atomicAdd(&cur[d4.z], 1)] = s4.z;
        ents[atomicAdd(&cur[d4.w], 1)] = s4.w;
    }
    for (int u = (e & ~3) + tid; u < e; u += gridDim.x * 256)
        ents[atomicAdd(&cur[dst[u]], 1)] = src[u];
}

// h1s = fp16( (x @ W1) * dis ) — outer-product GEMM, block tile 64x64, K=128.
#define SA 132
__global__ __launch_bounds__(256) void k_gemm1(
        const float* __restrict__ x, const float* __restrict__ W1,
        const float* __restrict__ dis, __half* __restrict__ h1s, int n) {
    __shared__ float Xs[64 * SA];    // 33 KB
    __shared__ float Ws[128 * 64];   // 32 KB
    int t = threadIdx.x;
    int nbase = blockIdx.x * 64;
    for (int i = t; i < 2048; i += 256)
        ((float4*)Ws)[i] = ((const float4*)W1)[i];
    for (int i = t; i < 2048; i += 256) {
        int row = i >> 5, q = i & 31;
        int r = nbase + row; if (r >= n) r = n - 1;
        float4 v = ((const float4*)(x + (size_t)r * 128))[q];
        *(float4*)&Xs[row * SA + q * 4] = v;
    }
    __syncthreads();
    int wid = t >> 6, lane = t & 63;
    int lx = lane & 7, ly = lane >> 3;
    int wm = wid & 1, wn = wid >> 1;
    int row0 = wm * 32 + ly * 4;
    int col0 = wn * 32 + lx * 4;
    float4 acc0 = {0.f,0.f,0.f,0.f}, acc1 = acc0, acc2 = acc0, acc3 = acc0;
#pragma unroll 4
    for (int k4 = 0; k4 < 32; ++k4) {
        int k = k4 * 4;
        float4 a0 = *(const float4*)&Xs[(row0 + 0) * SA + k];
        float4 a1 = *(const float4*)&Xs[(row0 + 1) * SA + k];
        float4 a2 = *(const float4*)&Xs[(row0 + 2) * SA + k];
        float4 a3 = *(const float4*)&Xs[(row0 + 3) * SA + k];
        float4 b0 = *(const float4*)&Ws[(k + 0) * 64 + col0];
        float4 b1 = *(const float4*)&Ws[(k + 1) * 64 + col0];
        float4 b2 = *(const float4*)&Ws[(k + 2) * 64 + col0];
        float4 b3 = *(const float4*)&Ws[(k + 3) * 64 + col0];
        f4fma(acc0, a0.x, b0); f4fma(acc0, a0.y, b1); f4fma(acc0, a0.z, b2); f4fma(acc0, a0.w, b3);
        f4fma(acc1, a1.x, b0); f4fma(acc1, a1.y, b1); f4fma(acc1, a1.z, b2); f4fma(acc1, a1.w, b3);
        f4fma(acc2, a2.x, b0); f4fma(acc2, a2.y, b1); f4fma(acc2, a2.z, b2); f4fma(acc2, a2.w, b3);
        f4fma(acc3, a3.x, b0); f4fma(acc3, a3.y, b1); f4fma(acc3, a3.z, b2); f4fma(acc3, a3.w, b3);
    }
    int grow = nbase + row0;
#pragma unroll
    for (int r = 0; r < 4; ++r) {
        int rr = grow + r;
        if (rr < n) {
            float d = dis[rr];
            float4 o = (r == 0) ? acc0 : (r == 1) ? acc1 : (r == 2) ? acc2 : acc3;
            o.x *= d; o.y *= d; o.z *= d; o.w *= d;
            h4store(&h1s[(size_t)rr * 64 + col0], o);
        }
    }
}

// Layer-1 aggregation + relu/b1 + gemm2, fused (one node per wave, 25K
// blocks).  fp16 row = 128 B = 8 lanes x 16 B: eg = lane>>3 (8 edge
// slots), fq = (lane&7)*8; one dwordx4 covers 8 edges.  v_fma_mix
// accumulate.  Shuffles all-lane (ds_bpermute from an inactive lane is
// undefined); only the add is predicated.  W2 column loaded from W2^T:
// 8 contiguous dwordx4 per lane (was 32 scalar loads).  xor-8/16/32
// reduce -> lanes 0-7 -> relu -> LDS row -> in-wave gemm2 -> h2s (fp16).
__global__ __launch_bounds__(256) void k_agg12(
        const __half* __restrict__ h1s, const int* __restrict__ ents,
        const int* __restrict__ rowptr, const int* __restrict__ deg,
        const float* __restrict__ dis, const float* __restrict__ b1,
        const float* __restrict__ W2T, __half* __restrict__ h2s, int n) {
    __shared__ float h1row[4][72];
    int wid = threadIdx.x >> 6, lane = threadIdx.x & 63;
    int v = blockIdx.x * 4 + wid;
    int vc = min(v, n - 1);            // no early return (syncthreads below)
    int start = rowptr[vc], cnt = deg[vc];
    int eg = lane >> 3;
    int fq = (lane & 7) * 8;           // half-index of this lane's 8 features
    int c = lane & 31, hh = lane >> 5;
    // preload W2 column c, k-range [hh*32, hh*32+32): 8 contiguous dwordx4
    float w2r[32];
    {
        const float4* wtp = (const float4*)&W2T[(size_t)c * 64 + hh * 32];
#pragma unroll
        for (int q = 0; q < 8; ++q)
            *(float4*)&w2r[q * 4] = wtp[q];
    }
    float4 accA = {0.f, 0.f, 0.f, 0.f}, accB = accA;
    if (cnt > 0 && cnt <= 64) {
        int pre = ents[start + min(lane, cnt - 1)];
        int ng = cnt >> 3;
#pragma unroll 4
        for (int g = 0; g < ng; ++g) {
            unsigned s = (unsigned)__shfl(pre, g * 8 + eg);
            h8acc(&h1s[(size_t)s * 64 + fq], accA, accB);
        }
        int rem = cnt & 7, j0 = cnt & ~7;
        if (rem) {
            unsigned s = (unsigned)__shfl(pre, j0 + (eg < rem ? eg : 0));
            float4 a, b; h8load(&h1s[(size_t)s * 64 + fq], a, b);
            if (eg < rem) { f4add(accA, a); f4add(accB, b); }
        }
    } else if (cnt > 64) {
        int j = 0;
        for (; j + 8 <= cnt; j += 8) {
            unsigned s = (unsigned)ents[start + j + eg];
            h8acc(&h1s[(size_t)s * 64 + fq], accA, accB);
        }
        int rem = cnt - j;
        if (rem) {
            unsigned s = (unsigned)ents[start + j + (eg < rem ? eg : 0)];
            float4 a, b; h8load(&h1s[(size_t)s * 64 + fq], a, b);
            if (eg < rem) { f4add(accA, a); f4add(accB, b); }
        }
    }
    if (eg == 0) {                     // self loop
        h8acc(&h1s[(size_t)vc * 64 + fq], accA, accB);
    }
    f4red(accA, 8);  f4red(accB, 8);
    f4red(accA, 16); f4red(accB, 16);
    f4red(accA, 32); f4red(accB, 32);
    float d = dis[vc];
    if (eg == 0) {
        float4 bq0 = *(const float4*)&b1[fq];
        float4 bq1 = *(const float4*)&b1[fq + 4];
        float4 o0, o1;
        o0.x = fmaxf(fmaf(d, accA.x, bq0.x), 0.f);
        o0.y = fmaxf(fmaf(d, accA.y, bq0.y), 0.f);
        o0.z = fmaxf(fmaf(d, accA.z, bq0.z), 0.f);
        o0.w = fmaxf(fmaf(d, accA.w, bq0.w), 0.f);
        o1.x = fmaxf(fmaf(d, accB.x, bq1.x), 0.f);
        o1.y = fmaxf(fmaf(d, accB.y, bq1.y), 0.f);
        o1.z = fmaxf(fmaf(d, accB.z, bq1.z), 0.f);
        o1.w = fmaxf(fmaf(d, accB.w, bq1.w), 0.f);
        *(float4*)&h1row[wid][fq] = o0;
        *(float4*)&h1row[wid][fq + 4] = o1;
    }
    __syncthreads();     // orders each wave's LDS row write before its reads
    // gemm2 in-wave: lane computes h2[c] partial over its k-half
    float p = 0.f;
#pragma unroll
    for (int j = 0; j < 32; j += 4) {
        float4 hv = *(const float4*)&h1row[wid][hh * 32 + j];
        p = fmaf(hv.x, w2r[j + 0], p);
        p = fmaf(hv.y, w2r[j + 1], p);
        p = fmaf(hv.z, w2r[j + 2], p);
        p = fmaf(hv.w, w2r[j + 3], p);
    }
    p += __shfl_xor(p, 32);
    if (hh == 0 && v < n) h2s[(size_t)v * 32 + c] = __float2half(p * d);
}

// layer-2 aggregation + relu + FC head.  fp16 row = 64 B = 4 lanes x 16 B:
// eg = lane>>2 (16 edge slots), fq = (lane&3)*8 halves; one dwordx4 covers
// 16 edges per instruction.  v_fma_mix accumulate; xor-4/8/16/32 reduce;
// FC in lanes 0-3.
__global__ void k_agg2(const __half* __restrict__ h2s, const int* __restrict__ ents,
                       const int* __restrict__ rowptr, const int* __restrict__ deg,
                       const float* __restrict__ dis, const float* __restrict__ b2,
                       const float* __restrict__ Wfc, const float* __restrict__ bfc,
                       float* __restrict__ out, int n) {
    int wid = threadIdx.x >> 6, lane = threadIdx.x & 63;
    int v = blockIdx.x * 4 + wid;
    if (v >= n) return;
    int start = rowptr[v], cnt = deg[v];
    int eg = lane >> 2;
    int fq = (lane & 3) * 8;
    float4 accA = {0.f, 0.f, 0.f, 0.f}, accB = accA;
    if (cnt > 0 && cnt <= 64) {
        int pre = ents[start + min(lane, cnt - 1)];
        int ng = cnt >> 4;
#pragma unroll 4
        for (int g = 0; g < ng; ++g) {
            unsigned s = (unsigned)__shfl(pre, g * 16 + eg);
            h8acc(&h2s[(size_t)s * 32 + fq], accA, accB);
        }
        int rem = cnt & 15, j0 = cnt & ~15;
        if (rem) {
            unsigned s = (unsigned)__shfl(pre, j0 + (eg < rem ? eg : 0));
            float4 a, b; h8load(&h2s[(size_t)s * 32 + fq], a, b);
            if (eg < rem) { f4add(accA, a); f4add(accB, b); }
        }
    } else if (cnt > 64) {
        int j = 0;
        for (; j + 16 <= cnt; j += 16) {
            unsigned s = (unsigned)ents[start + j + eg];
            h8acc(&h2s[(size_t)s * 32 + fq], accA, accB);
        }
        int rem = cnt - j;
        if (rem) {
            unsigned s = (unsigned)ents[start + j + (eg < rem ? eg : 0)];
            float4 a, b; h8load(&h2s[(size_t)s * 32 + fq], a, b);
            if (eg < rem) { f4add(accA, a); f4add(accB, b); }
        }
    }
    if (eg == 0) {                     // self loop (lanes 0-3)
        h8acc(&h2s[(size_t)v * 32 + fq], accA, accB);
    }
    f4red(accA, 4);  f4red(accB, 4);
    f4red(accA, 8);  f4red(accB, 8);
    f4red(accA, 16); f4red(accB, 16);
    f4red(accA, 32); f4red(accB, 32);
    float p = 0.f;
    if (eg == 0) {
        float d = dis[v];
        float4 bq0 = *(const float4*)&b2[fq];
        float4 bq1 = *(const float4*)&b2[fq + 4];
        float4 wq0 = *(const float4*)&Wfc[fq];
        float4 wq1 = *(const float4*)&Wfc[fq + 4];
        p  = fmaxf(fmaf(d, accA.x, bq0.x), 0.f) * wq0.x;
        p += fmaxf(fmaf(d, accA.y, bq0.y), 0.f) * wq0.y;
        p += fmaxf(fmaf(d, accA.z, bq0.z), 0.f) * wq0.z;
        p += fmaxf(fmaf(d, accA.w, bq0.w), 0.f) * wq0.w;
        p += fmaxf(fmaf(d, accB.x, bq1.x), 0.f) * wq1.x;
        p += fmaxf(fmaf(d, accB.y, bq1.y), 0.f) * wq1.y;
        p += fmaxf(fmaf(d, accB.z, bq1.z), 0.f) * wq1.z;
        p += fmaxf(fmaf(d, accB.w, bq1.w), 0.f) * wq1.w;
    }
    p += __shfl_xor(p, 1); p += __shfl_xor(p, 2);
    if (lane == 0) out[v] = p + bfc[0];
}

extern "C" void kernel_launch(void* const* d_in, const int* in_sizes, int n_in,
                              void* d_out, int out_size, void* d_ws, size_t ws_size,
                              hipStream_t stream) {
    const float* x   = (const float*)d_in[0];
    const int*   ei  = (const int*)d_in[1];
    const float* W1  = (const float*)d_in[2];
    const float* b1  = (const float*)d_in[3];
    const float* W2  = (const float*)d_in[4];
    const float* b2  = (const float*)d_in[5];
    const float* Wfc = (const float*)d_in[6];
    const float* bfc = (const float*)d_in[7];
    float* out = (float*)d_out;

    const int n = in_sizes[0] / 128;       // 100000
    const int e = in_sizes[1] / 2;         // 3200000
    const int* src = ei;
    const int* dst = ei + e;

    char* p = (char*)d_ws;
    size_t off = 0;
    auto carve = [&](size_t bytes) { void* r = p + off; off = (off + bytes + 255) & ~(size_t)255; return r; };
    int*   deg     = (int*)  carve((size_t)n * 4);
    int*   rowptr  = (int*)  carve((size_t)n * 4);
    int*   cur     = (int*)  carve((size_t)n * 4);
    float* dis     = (float*)carve((size_t)n * 4);
    int*   part    = (int*)  carve(256 * 4);
    float* W2T     = (float*)carve(2048 * 4);
    int*   ebuf2   = (int*)  carve((size_t)e * 4);
    __half* h2s    = (__half*)carve((size_t)n * 32 * 2);
    __half* h1s    = (__half*)carve((size_t)n * 64 * 2);
    (void)ws_size;

    const int nblk_scan = (n + SCAN_CHUNK - 1) / SCAN_CHUNK;   // 98 (<=256)
    const int nblk_e = (e / 4 + 255) / 256;                    // 3125

    hipMemsetAsync(deg, 0, (size_t)n * 4, stream);
    k_deg<<<nblk_e, 256, 0, stream>>>(dst, deg, W2, W2T, e);
    k_gscan1<<<nblk_scan, 256, 0, stream>>>(deg, part, n);
    k_gscan2<<<nblk_scan, 256, 0, stream>>>(deg, part, rowptr, cur, dis, n, nblk_scan);
    k_scatter<<<nblk_e, 256, 0, stream>>>(src, dst, cur, ebuf2, e);
    k_gemm1<<<(n + 63) / 64, 256, 0, stream>>>(x, W1, dis, h1s, n);
    k_agg12<<<(n + 3) / 4, 256, 0, stream>>>(h1s, ebuf2, rowptr, deg, dis, b1, W2T, h2s, n);
    k_agg2<<<(n + 3) / 4, 256, 0, stream>>>(h2s, ebuf2, rowptr, deg, dis, b2, Wfc, bfc, out, n);
}

// Round 6
// 368.213 us; speedup vs baseline: 1.8983x; 1.8983x over previous
//
#include <hip/hip_runtime.h>
#include <hip/hip_bf16.h>
#include <hip/hip_fp16.h>

// GCN: h = relu(GCN(x,W1,b1)); h = relu(GCN(h,W2,b2)); out = h @ Wfc + bfc
// GCN(x,W,b)[d] = dis[d] * ( sum_{(s,d) in E} hs[s] + hs[d] ) + b
//   where hs[v] = (x[v]@W) * dis[v],  dis[v] = rsqrt(1 + indeg(v))
//
// Round-20: revert to the proven round-4 bucket pipeline (305.2 us).
// Round-19's direct per-node scatter was 270 us on its own: 100K
// independent 4-B write streams -> 195 MB write-allocate traffic +
// serialized atomicAdd->store latency chains (VALUBusy 0.26%).  The
// bucket scatter keeps 782 contiguous write streams per block -- keep it.
// New in k_agg12: (a) W2 column loaded from W2^T as 8 contiguous dwordx4
// (was 32 scalar loads; W2^T written by k_hist block 0); (b) the
// block-wide __syncthreads replaced by a wave-local LDS fence -- h1row
// rows are wave-private, so only same-wave ds_write->ds_read ordering is
// needed (per-wave in-order LDS + lgkmcnt(0)); waves no longer wait on
// sibling waves' degree skew; (c) 32-bit gather addressing.

#define SCAN_CHUNK 1024
#define BSHIFT 7
#define BSIZE 128            // dsts per bucket
#define B1 256               // blocks in hist/binscatter passes
#define CSR_CAP 5120         // max staged bucket size (avg ~4092, +5sigma ~4400)

__device__ inline void f4fma(float4& a, float s, const float4& b) {
    a.x = fmaf(s, b.x, a.x); a.y = fmaf(s, b.y, a.y);
    a.z = fmaf(s, b.z, a.z); a.w = fmaf(s, b.w, a.w);
}
__device__ inline void f4add(float4& a, const float4& b) {
    a.x += b.x; a.y += b.y; a.z += b.z; a.w += b.w;
}
__device__ inline void f4red(float4& a, int off) {
    a.x += __shfl_xor(a.x, off); a.y += __shfl_xor(a.y, off);
    a.z += __shfl_xor(a.z, off); a.w += __shfl_xor(a.w, off);
}
// 8 halves (16 B) -> two float4 (single dwordx4 load)
__device__ inline void h8load(const __half* p, float4& a, float4& b) {
    uint4 r = *(const uint4*)p;
    __half2* h = (__half2*)&r;
    float2 f0 = __half22float2(h[0]);
    float2 f1 = __half22float2(h[1]);
    float2 f2 = __half22float2(h[2]);
    float2 f3 = __half22float2(h[3]);
    a = make_float4(f0.x, f0.y, f1.x, f1.y);
    b = make_float4(f2.x, f2.y, f3.x, f3.y);
}
// acc two packed halves into two f32 accumulators: one v_fma_mix each.
// fma(cvt_f32(h), 1.0f, acc) -- exact convert, single-rounded fma ==
// bit-identical to cvt+add.
__device__ inline void hacc2(unsigned h, float& x, float& y) {
    asm("v_fma_mix_f32 %0, %2, %3, %0 op_sel:[0,0,0] op_sel_hi:[1,0,0]\n\t"
        "v_fma_mix_f32 %1, %2, %3, %1 op_sel:[1,0,0] op_sel_hi:[1,0,0]"
        : "+v"(x), "+v"(y)
        : "v"(h), "v"(1.0f));
}
// 8 halves (one dwordx4) accumulated into the 8 f32 lanes of a,b
__device__ inline void h8acc(const __half* p, float4& a, float4& b) {
    uint4 r = *(const uint4*)p;
    hacc2(r.x, a.x, a.y);
    hacc2(r.y, a.z, a.w);
    hacc2(r.z, b.x, b.y);
    hacc2(r.w, b.z, b.w);
}
__device__ inline void h4store(__half* p, float4 v) {
    __half2 a = __floats2half2_rn(v.x, v.y);
    __half2 b = __floats2half2_rn(v.z, v.w);
    uint2 r; r.x = *(uint*)&a; r.y = *(uint*)&b;
    *(uint2*)p = r;
}

// ---- generic exclusive scan (m ints, nblk = ceil(m/1024) <= 256) ----
__global__ void k_gscan1(const int* __restrict__ in, int* __restrict__ part, int m) {
    int t = threadIdx.x;
    int base = blockIdx.x * SCAN_CHUNK + t * 4;
    int s = 0;
    for (int u = 0; u < 4; ++u) { int i = base + u; if (i < m) s += in[i]; }
    for (int o = 32; o; o >>= 1) s += __shfl_down(s, o);
    __shared__ int ws[4];
    if ((t & 63) == 0) ws[t >> 6] = s;
    __syncthreads();
    if (t == 0) part[blockIdx.x] = ws[0] + ws[1] + ws[2] + ws[3];
}

__global__ void k_gscan2(const int* __restrict__ in, const int* __restrict__ part,
                         int* __restrict__ out, int m, int nblk) {
    int t = threadIdx.x;
    int b = blockIdx.x;
    int pv = (t < b && t < nblk) ? part[t] : 0;
    int ps = pv;
    for (int o = 32; o; o >>= 1) ps += __shfl_down(ps, o);
    __shared__ int sh[4];
    if ((t & 63) == 0) sh[t >> 6] = ps;
    __syncthreads();
    int blockoff = sh[0] + sh[1] + sh[2] + sh[3];

    int base = b * SCAN_CHUNK + t * 4;
    int v0 = 0, v1 = 0, v2 = 0, v3 = 0;
    if (base + 0 < m) v0 = in[base + 0];
    if (base + 1 < m) v1 = in[base + 1];
    if (base + 2 < m) v2 = in[base + 2];
    if (base + 3 < m) v3 = in[base + 3];
    int tot = v0 + v1 + v2 + v3;
    int lane = t & 63, wid = t >> 6;
    int incl = tot;
    for (int o = 1; o < 64; o <<= 1) { int u = __shfl_up(incl, o); if (lane >= o) incl += u; }
    int excl = incl - tot;
    __shared__ int wt[4];
    if (lane == 63) wt[wid] = incl;
    __syncthreads();
    int woff = 0;
    for (int w = 0; w < wid; ++w) woff += wt[w];
    int off = blockoff + woff + excl;
    if (base + 0 < m) out[base + 0] = off;
    if (base + 1 < m) out[base + 1] = off + v0;
    if (base + 2 < m) out[base + 2] = off + v0 + v1;
    if (base + 3 < m) out[base + 3] = off + v0 + v1 + v2;
}

// ---- pass 1a: per-block bucket histogram (LDS atomics, int4 reads) ----
// block 0 also writes W2^T (32x64 f32, 8 KB) for k_agg12's preload.
__global__ __launch_bounds__(256) void k_hist(const int* __restrict__ dst,
                                              int* __restrict__ ghist,
                                              const float* __restrict__ W2,
                                              float* __restrict__ W2T,
                                              int e, int echunk, int nbuck) {
    extern __shared__ int h[];   // nbuck ints
    int t = threadIdx.x, b = blockIdx.x;
    for (int i = t; i < nbuck; i += 256) h[i] = 0;
    __syncthreads();
    if (b == 0) {
        for (int j = t; j < 2048; j += 256)
            W2T[j] = W2[(j & 63) * 32 + (j >> 6)];
    }
    int s = b * echunk, epd = min(e, s + echunk);
    for (int i = s + t * 4; i < epd; i += 1024) {
        if (i + 3 < epd) {
            int4 d4 = *(const int4*)&dst[i];
            atomicAdd(&h[d4.x >> BSHIFT], 1);
            atomicAdd(&h[d4.y >> BSHIFT], 1);
            atomicAdd(&h[d4.z >> BSHIFT], 1);
            atomicAdd(&h[d4.w >> BSHIFT], 1);
        } else {
            for (int u = i; u < epd; ++u) atomicAdd(&h[dst[u] >> BSHIFT], 1);
        }
    }
    __syncthreads();
    for (int k = t; k < nbuck; k += 256)
        ghist[k * B1 + b] = h[k];
}

// ---- pass 1b: scatter packed (src<<7|dlow) into bucket-ordered ebuf ----
__global__ __launch_bounds__(256) void k_binscatter(
        const int* __restrict__ src, const int* __restrict__ dst,
        const int* __restrict__ ghist_s, int* __restrict__ ebuf,
        int e, int echunk, int nbuck) {
    extern __shared__ int cur[];   // nbuck ints
    int t = threadIdx.x, b = blockIdx.x;
    for (int k = t; k < nbuck; k += 256)
        cur[k] = ghist_s[k * B1 + b];
    __syncthreads();
    int s = b * echunk, epd = min(e, s + echunk);
    for (int i = s + t * 4; i < epd; i += 1024) {
        if (i + 3 < epd) {
            int4 d4 = *(const int4*)&dst[i];
            int4 s4 = *(const int4*)&src[i];
            int p0 = atomicAdd(&cur[d4.x >> BSHIFT], 1);
            int p1 = atomicAdd(&cur[d4.y >> BSHIFT], 1);
            int p2 = atomicAdd(&cur[d4.z >> BSHIFT], 1);
            int p3 = atomicAdd(&cur[d4.w >> BSHIFT], 1);
            ebuf[p0] = (s4.x << BSHIFT) | (d4.x & (BSIZE - 1));
            ebuf[p1] = (s4.y << BSHIFT) | (d4.y & (BSIZE - 1));
            ebuf[p2] = (s4.z << BSHIFT) | (d4.z & (BSIZE - 1));
            ebuf[p3] = (s4.w << BSHIFT) | (d4.w & (BSIZE - 1));
        } else {
            for (int u = i; u < epd; ++u) {
                int d = dst[u];
                int pos = atomicAdd(&cur[d >> BSHIFT], 1);
                ebuf[pos] = (src[u] << BSHIFT) | (d & (BSIZE - 1));
            }
        }
    }
}

// ---- pass 2: per-bucket dst counting sort -> ebuf2 (bucket-local CSR) ----
__global__ __launch_bounds__(256) void k_csr(
        const int* __restrict__ ebuf, const int* __restrict__ ghist_s,
        int* __restrict__ ebuf2, int* __restrict__ rowptr, int* __restrict__ degi,
        float* __restrict__ dis, int n, int e, int nbuck) {
    int k = blockIdx.x, t = threadIdx.x;
    int estart = ghist_s[k * B1];
    int eend = (k + 1 < nbuck) ? ghist_s[(k + 1) * B1] : e;
    int ecnt = eend - estart;
    __shared__ int ein[CSR_CAP];
    __shared__ int eout[CSR_CAP];
    __shared__ int cnt[BSIZE];
    __shared__ int cur[BSIZE];
    __shared__ int wt[4];
    if (t < BSIZE) cnt[t] = 0;
    bool staged = (ecnt <= CSR_CAP);
    if (staged) {
        for (int i = t; i < ecnt; i += 256) ein[i] = ebuf[estart + i];
    }
    __syncthreads();
    if (staged) {
        for (int i = t; i < ecnt; i += 256)
            atomicAdd(&cnt[ein[i] & (BSIZE - 1)], 1);
    } else {
        for (int i = estart + t; i < eend; i += 256)
            atomicAdd(&cnt[ebuf[i] & (BSIZE - 1)], 1);
    }
    __syncthreads();
    int v = (t < BSIZE) ? cnt[t] : 0;
    int lane = t & 63, wid = t >> 6;
    int incl = v;
    for (int o = 1; o < 64; o <<= 1) { int u = __shfl_up(incl, o); if (lane >= o) incl += u; }
    if (lane == 63) wt[wid] = incl;
    __syncthreads();
    int woff = (wid == 1) ? wt[0] : 0;
    int excl = woff + incl - v;
    if (t < BSIZE) {
        cur[t] = excl;                       // bucket-local offset
        int node = k * BSIZE + t;
        if (node < n) {
            rowptr[node] = estart + excl;
            degi[node]   = v;
            dis[node]    = rsqrtf((float)(v + 1));
        }
    }
    __syncthreads();
    if (staged) {
        for (int i = t; i < ecnt; i += 256) {
            int w = ein[i];
            int pos = atomicAdd(&cur[w & (BSIZE - 1)], 1);
            eout[pos] = w;                   // scatter stays in LDS
        }
        __syncthreads();
        for (int i = t; i < ecnt; i += 256)  // coalesced write-out
            ebuf2[estart + i] = eout[i];
    } else {
        for (int i = estart + t; i < eend; i += 256) {
            int w = ebuf[i];
            int pos = estart + atomicAdd(&cur[w & (BSIZE - 1)], 1);
            ebuf2[pos] = w;
        }
    }
}

// h1s = fp16( (x @ W1) * dis ) — outer-product GEMM, block tile 64x64, K=128.
#define SA 132
__global__ __launch_bounds__(256) void k_gemm1(
        const float* __restrict__ x, const float* __restrict__ W1,
        const float* __restrict__ dis, __half* __restrict__ h1s, int n) {
    __shared__ float Xs[64 * SA];    // 33 KB
    __shared__ float Ws[128 * 64];   // 32 KB
    int t = threadIdx.x;
    int nbase = blockIdx.x * 64;
    for (int i = t; i < 2048; i += 256)
        ((float4*)Ws)[i] = ((const float4*)W1)[i];
    for (int i = t; i < 2048; i += 256) {
        int row = i >> 5, q = i & 31;
        int r = nbase + row; if (r >= n) r = n - 1;
        float4 v = ((const float4*)(x + (size_t)r * 128))[q];
        *(float4*)&Xs[row * SA + q * 4] = v;
    }
    __syncthreads();
    int wid = t >> 6, lane = t & 63;
    int lx = lane & 7, ly = lane >> 3;
    int wm = wid & 1, wn = wid >> 1;
    int row0 = wm * 32 + ly * 4;
    int col0 = wn * 32 + lx * 4;
    float4 acc0 = {0.f,0.f,0.f,0.f}, acc1 = acc0, acc2 = acc0, acc3 = acc0;
#pragma unroll 4
    for (int k4 = 0; k4 < 32; ++k4) {
        int k = k4 * 4;
        float4 a0 = *(const float4*)&Xs[(row0 + 0) * SA + k];
        float4 a1 = *(const float4*)&Xs[(row0 + 1) * SA + k];
        float4 a2 = *(const float4*)&Xs[(row0 + 2) * SA + k];
        float4 a3 = *(const float4*)&Xs[(row0 + 3) * SA + k];
        float4 b0 = *(const float4*)&Ws[(k + 0) * 64 + col0];
        float4 b1 = *(const float4*)&Ws[(k + 1) * 64 + col0];
        float4 b2 = *(const float4*)&Ws[(k + 2) * 64 + col0];
        float4 b3 = *(const float4*)&Ws[(k + 3) * 64 + col0];
        f4fma(acc0, a0.x, b0); f4fma(acc0, a0.y, b1); f4fma(acc0, a0.z, b2); f4fma(acc0, a0.w, b3);
        f4fma(acc1, a1.x, b0); f4fma(acc1, a1.y, b1); f4fma(acc1, a1.z, b2); f4fma(acc1, a1.w, b3);
        f4fma(acc2, a2.x, b0); f4fma(acc2, a2.y, b1); f4fma(acc2, a2.z, b2); f4fma(acc2, a2.w, b3);
        f4fma(acc3, a3.x, b0); f4fma(acc3, a3.y, b1); f4fma(acc3, a3.z, b2); f4fma(acc3, a3.w, b3);
    }
    int grow = nbase + row0;
#pragma unroll
    for (int r = 0; r < 4; ++r) {
        int rr = grow + r;
        if (rr < n) {
            float d = dis[rr];
            float4 o = (r == 0) ? acc0 : (r == 1) ? acc1 : (r == 2) ? acc2 : acc3;
            o.x *= d; o.y *= d; o.z *= d; o.w *= d;
            h4store(&h1s[(size_t)rr * 64 + col0], o);
        }
    }
}

// Layer-1 aggregation + relu/b1 + gemm2, fused.  One node per wave, 25K
// blocks.  fp16 row = 128 B = 8 lanes x 16 B: eg = lane>>3 (8 edge slots),
// fq = (lane&7)*8; one dwordx4 covers 8 edges.  v_fma_mix accumulate.
// Shuffles all-lane (ds_bpermute from an inactive lane is undefined);
// only the add is predicated.  W2 column: 8 contiguous dwordx4 from W2^T.
// h1row is WAVE-PRIVATE ([wid]): the LDS write->read hand-off needs only
// same-wave ordering (per-wave in-order LDS + lgkmcnt(0) fence), so
// there is NO block barrier -- waves don't wait on sibling degree skew.
__global__ __launch_bounds__(256) void k_agg12(
        const __half* __restrict__ h1s, const int* __restrict__ ents,
        const int* __restrict__ rowptr, const int* __restrict__ degi,
        const float* __restrict__ dis, const float* __restrict__ b1,
        const float* __restrict__ W2T, __half* __restrict__ h2s, int n) {
    __shared__ float h1row[4][72];
    int wid = threadIdx.x >> 6, lane = threadIdx.x & 63;
    int v = blockIdx.x * 4 + wid;
    if (v >= n) return;
    int start = rowptr[v], cnt = degi[v];
    int eg = lane >> 3;
    int fq = (lane & 7) * 8;           // half-index of this lane's 8 features
    int c = lane & 31, hh = lane >> 5;
    // preload W2 column c, k-range [hh*32, hh*32+32): 8 contiguous dwordx4
    float w2r[32];
    {
        const float4* wtp = (const float4*)&W2T[(c << 6) + (hh << 5)];
#pragma unroll
        for (int q = 0; q < 8; ++q)
            *(float4*)&w2r[q * 4] = wtp[q];
    }
    float4 accA = {0.f, 0.f, 0.f, 0.f}, accB = accA;
    if (cnt > 0 && cnt <= 64) {
        int pre = ents[start + min(lane, cnt - 1)];
        int ng = cnt >> 3;
#pragma unroll 4
        for (int g = 0; g < ng; ++g) {
            unsigned s = ((unsigned)__shfl(pre, g * 8 + eg)) >> BSHIFT;
            h8acc(&h1s[(s << 6) + fq], accA, accB);
        }
        int rem = cnt & 7, j0 = cnt & ~7;
        if (rem) {
            unsigned s = ((unsigned)__shfl(pre, j0 + (eg < rem ? eg : 0))) >> BSHIFT;
            float4 a, b; h8load(&h1s[(s << 6) + fq], a, b);
            if (eg < rem) { f4add(accA, a); f4add(accB, b); }
        }
    } else if (cnt > 64) {
        int j = 0;
        for (; j + 8 <= cnt; j += 8) {
            unsigned s = ((unsigned)ents[start + j + eg]) >> BSHIFT;
            h8acc(&h1s[(s << 6) + fq], accA, accB);
        }
        int rem = cnt - j;
        if (rem) {
            unsigned s = ((unsigned)ents[start + j + (eg < rem ? eg : 0)]) >> BSHIFT;
            float4 a, b; h8load(&h1s[(s << 6) + fq], a, b);
            if (eg < rem) { f4add(accA, a); f4add(accB, b); }
        }
    }
    {   // self loop
        unsigned sv = (unsigned)v;
        if (eg == 0) h8acc(&h1s[(sv << 6) + fq], accA, accB);
    }
    f4red(accA, 8);  f4red(accB, 8);
    f4red(accA, 16); f4red(accB, 16);
    f4red(accA, 32); f4red(accB, 32);
    float d = dis[v];
    if (eg == 0) {
        float4 bq0 = *(const float4*)&b1[fq];
        float4 bq1 = *(const float4*)&b1[fq + 4];
        float4 o0, o1;
        o0.x = fmaxf(fmaf(d, accA.x, bq0.x), 0.f);
        o0.y = fmaxf(fmaf(d, accA.y, bq0.y), 0.f);
        o0.z = fmaxf(fmaf(d, accA.z, bq0.z), 0.f);
        o0.w = fmaxf(fmaf(d, accA.w, bq0.w), 0.f);
        o1.x = fmaxf(fmaf(d, accB.x, bq1.x), 0.f);
        o1.y = fmaxf(fmaf(d, accB.y, bq1.y), 0.f);
        o1.z = fmaxf(fmaf(d, accB.z, bq1.z), 0.f);
        o1.w = fmaxf(fmaf(d, accB.w, bq1.w), 0.f);
        *(float4*)&h1row[wid][fq] = o0;
        *(float4*)&h1row[wid][fq + 4] = o1;
    }
    // wave-local fence: ds_writes above complete (in-order LDS, lgkmcnt)
    // before the ds_reads below; "memory" stops compiler reordering.
    asm volatile("s_waitcnt lgkmcnt(0)" ::: "memory");
    // gemm2 in-wave: lane computes h2[c] partial over its k-half
    float p = 0.f;
#pragma unroll
    for (int j = 0; j < 32; j += 4) {
        float4 hv = *(const float4*)&h1row[wid][hh * 32 + j];
        p = fmaf(hv.x, w2r[j + 0], p);
        p = fmaf(hv.y, w2r[j + 1], p);
        p = fmaf(hv.z, w2r[j + 2], p);
        p = fmaf(hv.w, w2r[j + 3], p);
    }
    p += __shfl_xor(p, 32);
    if (hh == 0) h2s[(size_t)v * 32 + c] = __float2half(p * d);
}

// layer-2 aggregation + relu + FC head.  fp16 row = 64 B = 4 lanes x 16 B:
// eg = lane>>2 (16 edge slots), fq = (lane&3)*8 halves; one dwordx4 covers
// 16 edges per instruction.  v_fma_mix accumulate; xor-4/8/16/32 reduce;
// FC in lanes 0-3.
__global__ void k_agg2(const __half* __restrict__ h2s, const int* __restrict__ ents,
                       const int* __restrict__ rowptr, const int* __restrict__ degi,
                       const float* __restrict__ dis, const float* __restrict__ b2,
                       const float* __restrict__ Wfc, const float* __restrict__ bfc,
                       float* __restrict__ out, int n) {
    int wid = threadIdx.x >> 6, lane = threadIdx.x & 63;
    int v = blockIdx.x * 4 + wid;
    if (v >= n) return;
    int start = rowptr[v], cnt = degi[v];
    int eg = lane >> 2;
    int fq = (lane & 3) * 8;
    float4 accA = {0.f, 0.f, 0.f, 0.f}, accB = accA;
    if (cnt > 0 && cnt <= 64) {
        int pre = ents[start + min(lane, cnt - 1)];
        int ng = cnt >> 4;
#pragma unroll 4
        for (int g = 0; g < ng; ++g) {
            unsigned s = ((unsigned)__shfl(pre, g * 16 + eg)) >> BSHIFT;
            h8acc(&h2s[(s << 5) + fq], accA, accB);
        }
        int rem = cnt & 15, j0 = cnt & ~15;
        if (rem) {
            unsigned s = ((unsigned)__shfl(pre, j0 + (eg < rem ? eg : 0))) >> BSHIFT;
            float4 a, b; h8load(&h2s[(s << 5) + fq], a, b);
            if (eg < rem) { f4add(accA, a); f4add(accB, b); }
        }
    } else if (cnt > 64) {
        int j = 0;
        for (; j + 16 <= cnt; j += 16) {
            unsigned s = ((unsigned)ents[start + j + eg]) >> BSHIFT;
            h8acc(&h2s[(s << 5) + fq], accA, accB);
        }
        int rem = cnt - j;
        if (rem) {
            unsigned s = ((unsigned)ents[start + j + (eg < rem ? eg : 0)]) >> BSHIFT;
            float4 a, b; h8load(&h2s[(s << 5) + fq], a, b);
            if (eg < rem) { f4add(accA, a); f4add(accB, b); }
        }
    }
    if (eg == 0) {                     // self loop (lanes 0-3)
        unsigned sv = (unsigned)v;
        h8acc(&h2s[(sv << 5) + fq], accA, accB);
    }
    f4red(accA, 4);  f4red(accB, 4);
    f4red(accA, 8);  f4red(accB, 8);
    f4red(accA, 16); f4red(accB, 16);
    f4red(accA, 32); f4red(accB, 32);
    float p = 0.f;
    if (eg == 0) {
        float d = dis[v];
        float4 bq0 = *(const float4*)&b2[fq];
        float4 bq1 = *(const float4*)&b2[fq + 4];
        float4 wq0 = *(const float4*)&Wfc[fq];
        float4 wq1 = *(const float4*)&Wfc[fq + 4];
        p  = fmaxf(fmaf(d, accA.x, bq0.x), 0.f) * wq0.x;
        p += fmaxf(fmaf(d, accA.y, bq0.y), 0.f) * wq0.y;
        p += fmaxf(fmaf(d, accA.z, bq0.z), 0.f) * wq0.z;
        p += fmaxf(fmaf(d, accA.w, bq0.w), 0.f) * wq0.w;
        p += fmaxf(fmaf(d, accB.x, bq1.x), 0.f) * wq1.x;
        p += fmaxf(fmaf(d, accB.y, bq1.y), 0.f) * wq1.y;
        p += fmaxf(fmaf(d, accB.z, bq1.z), 0.f) * wq1.z;
        p += fmaxf(fmaf(d, accB.w, bq1.w), 0.f) * wq1.w;
    }
    p += __shfl_xor(p, 1); p += __shfl_xor(p, 2);
    if (lane == 0) out[v] = p + bfc[0];
}

extern "C" void kernel_launch(void* const* d_in, const int* in_sizes, int n_in,
                              void* d_out, int out_size, void* d_ws, size_t ws_size,
                              hipStream_t stream) {
    const float* x   = (const float*)d_in[0];
    const int*   ei  = (const int*)d_in[1];
    const float* W1  = (const float*)d_in[2];
    const float* b1  = (const float*)d_in[3];
    const float* W2  = (const float*)d_in[4];
    const float* b2  = (const float*)d_in[5];
    const float* Wfc = (const float*)d_in[6];
    const float* bfc = (const float*)d_in[7];
    float* out = (float*)d_out;

    const int n = in_sizes[0] / 128;       // 100000
    const int e = in_sizes[1] / 2;         // 3200000
    const int* src = ei;
    const int* dst = ei + e;

    const int nbuck = (n + BSIZE - 1) / BSIZE;           // 782
    const int m = nbuck * B1;                            // 200192
    const int echunk = (e + B1 - 1) / B1;                // 12500

    char* p = (char*)d_ws;
    size_t off = 0;
    auto carve = [&](size_t bytes) { void* r = p + off; off = (off + bytes + 255) & ~(size_t)255; return r; };
    int*   ghist   = (int*)  carve((size_t)m * 4);
    int*   ghist_s = (int*)  carve((size_t)m * 4);
    int*   part    = (int*)  carve(256 * 4);
    float* dis     = (float*)carve((size_t)n * 4);
    int*   rowptr  = (int*)  carve((size_t)n * 4);
    int*   degi    = (int*)  carve((size_t)n * 4);
    float* W2T     = (float*)carve(2048 * 4);
    int*   ebuf2   = (int*)  carve((size_t)e * 4);
    __half* h2s    = (__half*)carve((size_t)n * 32 * 2);
    void*  ebuf_or_h1s = carve((size_t)e * 4);           // ebuf(E*4) aliases h1s(N*64*2)
    int*    ebuf = (int*)ebuf_or_h1s;
    __half* h1s  = (__half*)ebuf_or_h1s;
    (void)ws_size;

    const int nblk_scan = (m + SCAN_CHUNK - 1) / SCAN_CHUNK;   // 196 (<=256)
    const size_t lds_buck = (size_t)nbuck * 4;

    k_hist<<<B1, 256, lds_buck, stream>>>(dst, ghist, W2, W2T, e, echunk, nbuck);
    k_gscan1<<<nblk_scan, 256, 0, stream>>>(ghist, part, m);
    k_gscan2<<<nblk_scan, 256, 0, stream>>>(ghist, part, ghist_s, m, nblk_scan);
    k_binscatter<<<B1, 256, lds_buck, stream>>>(src, dst, ghist_s, ebuf, e, echunk, nbuck);
    k_csr<<<nbuck, 256, 0, stream>>>(ebuf, ghist_s, ebuf2, rowptr, degi, dis, n, e, nbuck);
    k_gemm1<<<(n + 63) / 64, 256, 0, stream>>>(x, W1, dis, h1s, n);
    k_agg12<<<(n + 3) / 4, 256, 0, stream>>>(h1s, ebuf2, rowptr, degi, dis, b1, W2T, h2s, n);
    k_agg2<<<(n + 3) / 4, 256, 0, stream>>>(h2s, ebuf2, rowptr, degi, dis, b2, Wfc, bfc, out, n);
}

// Round 8
// 360.117 us; speedup vs baseline: 1.9409x; 1.0225x over previous
//
#include <hip/hip_runtime.h>
#include <hip/hip_bf16.h>
#include <hip/hip_fp16.h>

// GCN: h = relu(GCN(x,W1,b1)); h = relu(GCN(h,W2,b2)); out = h @ Wfc + bfc
// GCN(x,W,b)[d] = dis[d] * ( sum_{(s,d) in E} hs[s] + hs[d] ) + b
//   where hs[v] = (x[v]@W) * dis[v],  dis[v] = rsqrt(1 + indeg(v))
//
// Round-22: resubmit of round-21 (infra failure, never measured).
// Round-21: revert round-6's regression.  The asm "s_waitcnt lgkmcnt(0)"
// + "memory"-clobber fence halved k_agg12's issue rate (73 -> 140 us,
// VALUBusy 52 -> 26%) -- hand fences defeat the scheduler; structured
// __syncthreads is back.  Kernel is the round-4 73-us form with ONE
// isolated change: the W2 column preload is 8 contiguous dwordx4 from
// W2^T (transpose written by k_hist block 0; correctness proven in
// round 6), placed AFTER the gather+reduce so the 32 w2r VGPRs are not
// live through the gather and the load latency hides under the barrier.

#define SCAN_CHUNK 1024
#define BSHIFT 7
#define BSIZE 128            // dsts per bucket
#define B1 256               // blocks in hist/binscatter passes
#define CSR_CAP 5120         // max staged bucket size (avg ~4092, +5sigma ~4400)

__device__ inline void f4fma(float4& a, float s, const float4& b) {
    a.x = fmaf(s, b.x, a.x); a.y = fmaf(s, b.y, a.y);
    a.z = fmaf(s, b.z, a.z); a.w = fmaf(s, b.w, a.w);
}
__device__ inline void f4add(float4& a, const float4& b) {
    a.x += b.x; a.y += b.y; a.z += b.z; a.w += b.w;
}
__device__ inline void f4red(float4& a, int off) {
    a.x += __shfl_xor(a.x, off); a.y += __shfl_xor(a.y, off);
    a.z += __shfl_xor(a.z, off); a.w += __shfl_xor(a.w, off);
}
// 8 halves (16 B) -> two float4 (single dwordx4 load)
__device__ inline void h8load(const __half* p, float4& a, float4& b) {
    uint4 r = *(const uint4*)p;
    __half2* h = (__half2*)&r;
    float2 f0 = __half22float2(h[0]);
    float2 f1 = __half22float2(h[1]);
    float2 f2 = __half22float2(h[2]);
    float2 f3 = __half22float2(h[3]);
    a = make_float4(f0.x, f0.y, f1.x, f1.y);
    b = make_float4(f2.x, f2.y, f3.x, f3.y);
}
// acc two packed halves into two f32 accumulators: one v_fma_mix each.
// fma(cvt_f32(h), 1.0f, acc) -- exact convert, single-rounded fma ==
// bit-identical to cvt+add.
__device__ inline void hacc2(unsigned h, float& x, float& y) {
    asm("v_fma_mix_f32 %0, %2, %3, %0 op_sel:[0,0,0] op_sel_hi:[1,0,0]\n\t"
        "v_fma_mix_f32 %1, %2, %3, %1 op_sel:[1,0,0] op_sel_hi:[1,0,0]"
        : "+v"(x), "+v"(y)
        : "v"(h), "v"(1.0f));
}
// 8 halves (one dwordx4) accumulated into the 8 f32 lanes of a,b
__device__ inline void h8acc(const __half* p, float4& a, float4& b) {
    uint4 r = *(const uint4*)p;
    hacc2(r.x, a.x, a.y);
    hacc2(r.y, a.z, a.w);
    hacc2(r.z, b.x, b.y);
    hacc2(r.w, b.z, b.w);
}
__device__ inline void h4store(__half* p, float4 v) {
    __half2 a = __floats2half2_rn(v.x, v.y);
    __half2 b = __floats2half2_rn(v.z, v.w);
    uint2 r; r.x = *(uint*)&a; r.y = *(uint*)&b;
    *(uint2*)p = r;
}

// ---- generic exclusive scan (m ints, nblk = ceil(m/1024) <= 256) ----
__global__ void k_gscan1(const int* __restrict__ in, int* __restrict__ part, int m) {
    int t = threadIdx.x;
    int base = blockIdx.x * SCAN_CHUNK + t * 4;
    int s = 0;
    for (int u = 0; u < 4; ++u) { int i = base + u; if (i < m) s += in[i]; }
    for (int o = 32; o; o >>= 1) s += __shfl_down(s, o);
    __shared__ int ws[4];
    if ((t & 63) == 0) ws[t >> 6] = s;
    __syncthreads();
    if (t == 0) part[blockIdx.x] = ws[0] + ws[1] + ws[2] + ws[3];
}

__global__ void k_gscan2(const int* __restrict__ in, const int* __restrict__ part,
                         int* __restrict__ out, int m, int nblk) {
    int t = threadIdx.x;
    int b = blockIdx.x;
    int pv = (t < b && t < nblk) ? part[t] : 0;
    int ps = pv;
    for (int o = 32; o; o >>= 1) ps += __shfl_down(ps, o);
    __shared__ int sh[4];
    if ((t & 63) == 0) sh[t >> 6] = ps;
    __syncthreads();
    int blockoff = sh[0] + sh[1] + sh[2] + sh[3];

    int base = b * SCAN_CHUNK + t * 4;
    int v0 = 0, v1 = 0, v2 = 0, v3 = 0;
    if (base + 0 < m) v0 = in[base + 0];
    if (base + 1 < m) v1 = in[base + 1];
    if (base + 2 < m) v2 = in[base + 2];
    if (base + 3 < m) v3 = in[base + 3];
    int tot = v0 + v1 + v2 + v3;
    int lane = t & 63, wid = t >> 6;
    int incl = tot;
    for (int o = 1; o < 64; o <<= 1) { int u = __shfl_up(incl, o); if (lane >= o) incl += u; }
    int excl = incl - tot;
    __shared__ int wt[4];
    if (lane == 63) wt[wid] = incl;
    __syncthreads();
    int woff = 0;
    for (int w = 0; w < wid; ++w) woff += wt[w];
    int off = blockoff + woff + excl;
    if (base + 0 < m) out[base + 0] = off;
    if (base + 1 < m) out[base + 1] = off + v0;
    if (base + 2 < m) out[base + 2] = off + v0 + v1;
    if (base + 3 < m) out[base + 3] = off + v0 + v1 + v2;
}

// ---- pass 1a: per-block bucket histogram (LDS atomics, int4 reads) ----
// block 0 also writes W2^T (32x64 f32, 8 KB) for k_agg12's preload.
__global__ __launch_bounds__(256) void k_hist(const int* __restrict__ dst,
                                              int* __restrict__ ghist,
                                              const float* __restrict__ W2,
                                              float* __restrict__ W2T,
                                              int e, int echunk, int nbuck) {
    extern __shared__ int h[];   // nbuck ints
    int t = threadIdx.x, b = blockIdx.x;
    for (int i = t; i < nbuck; i += 256) h[i] = 0;
    __syncthreads();
    if (b == 0) {
        for (int j = t; j < 2048; j += 256)
            W2T[j] = W2[(j & 63) * 32 + (j >> 6)];
    }
    int s = b * echunk, epd = min(e, s + echunk);
    for (int i = s + t * 4; i < epd; i += 1024) {
        if (i + 3 < epd) {
            int4 d4 = *(const int4*)&dst[i];
            atomicAdd(&h[d4.x >> BSHIFT], 1);
            atomicAdd(&h[d4.y >> BSHIFT], 1);
            atomicAdd(&h[d4.z >> BSHIFT], 1);
            atomicAdd(&h[d4.w >> BSHIFT], 1);
        } else {
            for (int u = i; u < epd; ++u) atomicAdd(&h[dst[u] >> BSHIFT], 1);
        }
    }
    __syncthreads();
    for (int k = t; k < nbuck; k += 256)
        ghist[k * B1 + b] = h[k];
}

// ---- pass 1b: scatter packed (src<<7|dlow) into bucket-ordered ebuf ----
__global__ __launch_bounds__(256) void k_binscatter(
        const int* __restrict__ src, const int* __restrict__ dst,
        const int* __restrict__ ghist_s, int* __restrict__ ebuf,
        int e, int echunk, int nbuck) {
    extern __shared__ int cur[];   // nbuck ints
    int t = threadIdx.x, b = blockIdx.x;
    for (int k = t; k < nbuck; k += 256)
        cur[k] = ghist_s[k * B1 + b];
    __syncthreads();
    int s = b * echunk, epd = min(e, s + echunk);
    for (int i = s + t * 4; i < epd; i += 1024) {
        if (i + 3 < epd) {
            int4 d4 = *(const int4*)&dst[i];
            int4 s4 = *(const int4*)&src[i];
            int p0 = atomicAdd(&cur[d4.x >> BSHIFT], 1);
            int p1 = atomicAdd(&cur[d4.y >> BSHIFT], 1);
            int p2 = atomicAdd(&cur[d4.z >> BSHIFT], 1);
            int p3 = atomicAdd(&cur[d4.w >> BSHIFT], 1);
            ebuf[p0] = (s4.x << BSHIFT) | (d4.x & (BSIZE - 1));
            ebuf[p1] = (s4.y << BSHIFT) | (d4.y & (BSIZE - 1));
            ebuf[p2] = (s4.z << BSHIFT) | (d4.z & (BSIZE - 1));
            ebuf[p3] = (s4.w << BSHIFT) | (d4.w & (BSIZE - 1));
        } else {
            for (int u = i; u < epd; ++u) {
                int d = dst[u];
                int pos = atomicAdd(&cur[d >> BSHIFT], 1);
                ebuf[pos] = (src[u] << BSHIFT) | (d & (BSIZE - 1));
            }
        }
    }
}

// ---- pass 2: per-bucket dst counting sort -> ebuf2 (bucket-local CSR) ----
__global__ __launch_bounds__(256) void k_csr(
        const int* __restrict__ ebuf, const int* __restrict__ ghist_s,
        int* __restrict__ ebuf2, int* __restrict__ rowptr, int* __restrict__ degi,
        float* __restrict__ dis, int n, int e, int nbuck) {
    int k = blockIdx.x, t = threadIdx.x;
    int estart = ghist_s[k * B1];
    int eend = (k + 1 < nbuck) ? ghist_s[(k + 1) * B1] : e;
    int ecnt = eend - estart;
    __shared__ int ein[CSR_CAP];
    __shared__ int eout[CSR_CAP];
    __shared__ int cnt[BSIZE];
    __shared__ int cur[BSIZE];
    __shared__ int wt[4];
    if (t < BSIZE) cnt[t] = 0;
    bool staged = (ecnt <= CSR_CAP);
    if (staged) {
        for (int i = t; i < ecnt; i += 256) ein[i] = ebuf[estart + i];
    }
    __syncthreads();
    if (staged) {
        for (int i = t; i < ecnt; i += 256)
            atomicAdd(&cnt[ein[i] & (BSIZE - 1)], 1);
    } else {
        for (int i = estart + t; i < eend; i += 256)
            atomicAdd(&cnt[ebuf[i] & (BSIZE - 1)], 1);
    }
    __syncthreads();
    int v = (t < BSIZE) ? cnt[t] : 0;
    int lane = t & 63, wid = t >> 6;
    int incl = v;
    for (int o = 1; o < 64; o <<= 1) { int u = __shfl_up(incl, o); if (lane >= o) incl += u; }
    if (lane == 63) wt[wid] = incl;
    __syncthreads();
    int woff = (wid == 1) ? wt[0] : 0;
    int excl = woff + incl - v;
    if (t < BSIZE) {
        cur[t] = excl;                       // bucket-local offset
        int node = k * BSIZE + t;
        if (node < n) {
            rowptr[node] = estart + excl;
            degi[node]   = v;
            dis[node]    = rsqrtf((float)(v + 1));
        }
    }
    __syncthreads();
    if (staged) {
        for (int i = t; i < ecnt; i += 256) {
            int w = ein[i];
            int pos = atomicAdd(&cur[w & (BSIZE - 1)], 1);
            eout[pos] = w;                   // scatter stays in LDS
        }
        __syncthreads();
        for (int i = t; i < ecnt; i += 256)  // coalesced write-out
            ebuf2[estart + i] = eout[i];
    } else {
        for (int i = estart + t; i < eend; i += 256) {
            int w = ebuf[i];
            int pos = estart + atomicAdd(&cur[w & (BSIZE - 1)], 1);
            ebuf2[pos] = w;
        }
    }
}

// h1s = fp16( (x @ W1) * dis ) — outer-product GEMM, block tile 64x64, K=128.
#define SA 132
__global__ __launch_bounds__(256) void k_gemm1(
        const float* __restrict__ x, const float* __restrict__ W1,
        const float* __restrict__ dis, __half* __restrict__ h1s, int n) {
    __shared__ float Xs[64 * SA];    // 33 KB
    __shared__ float Ws[128 * 64];   // 32 KB
    int t = threadIdx.x;
    int nbase = blockIdx.x * 64;
    for (int i = t; i < 2048; i += 256)
        ((float4*)Ws)[i] = ((const float4*)W1)[i];
    for (int i = t; i < 2048; i += 256) {
        int row = i >> 5, q = i & 31;
        int r = nbase + row; if (r >= n) r = n - 1;
        float4 v = ((const float4*)(x + (size_t)r * 128))[q];
        *(float4*)&Xs[row * SA + q * 4] = v;
    }
    __syncthreads();
    int wid = t >> 6, lane = t & 63;
    int lx = lane & 7, ly = lane >> 3;
    int wm = wid & 1, wn = wid >> 1;
    int row0 = wm * 32 + ly * 4;
    int col0 = wn * 32 + lx * 4;
    float4 acc0 = {0.f,0.f,0.f,0.f}, acc1 = acc0, acc2 = acc0, acc3 = acc0;
#pragma unroll 4
    for (int k4 = 0; k4 < 32; ++k4) {
        int k = k4 * 4;
        float4 a0 = *(const float4*)&Xs[(row0 + 0) * SA + k];
        float4 a1 = *(const float4*)&Xs[(row0 + 1) * SA + k];
        float4 a2 = *(const float4*)&Xs[(row0 + 2) * SA + k];
        float4 a3 = *(const float4*)&Xs[(row0 + 3) * SA + k];
        float4 b0 = *(const float4*)&Ws[(k + 0) * 64 + col0];
        float4 b1 = *(const float4*)&Ws[(k + 1) * 64 + col0];
        float4 b2 = *(const float4*)&Ws[(k + 2) * 64 + col0];
        float4 b3 = *(const float4*)&Ws[(k + 3) * 64 + col0];
        f4fma(acc0, a0.x, b0); f4fma(acc0, a0.y, b1); f4fma(acc0, a0.z, b2); f4fma(acc0, a0.w, b3);
        f4fma(acc1, a1.x, b0); f4fma(acc1, a1.y, b1); f4fma(acc1, a1.z, b2); f4fma(acc1, a1.w, b3);
        f4fma(acc2, a2.x, b0); f4fma(acc2, a2.y, b1); f4fma(acc2, a2.z, b2); f4fma(acc2, a2.w, b3);
        f4fma(acc3, a3.x, b0); f4fma(acc3, a3.y, b1); f4fma(acc3, a3.z, b2); f4fma(acc3, a3.w, b3);
    }
    int grow = nbase + row0;
#pragma unroll
    for (int r = 0; r < 4; ++r) {
        int rr = grow + r;
        if (rr < n) {
            float d = dis[rr];
            float4 o = (r == 0) ? acc0 : (r == 1) ? acc1 : (r == 2) ? acc2 : acc3;
            o.x *= d; o.y *= d; o.z *= d; o.w *= d;
            h4store(&h1s[(size_t)rr * 64 + col0], o);
        }
    }
}

// Layer-1 aggregation + relu/b1 + gemm2, fused (round-4 73-us form).
// One node per wave, 25K blocks.  fp16 row = 128 B = 8 lanes x 16 B:
// eg = lane>>3 (8 edge slots), fq = (lane&7)*8; one dwordx4 covers 8
// edges.  v_fma_mix accumulate.  Shuffles all-lane (ds_bpermute from an
// inactive lane is undefined); only the add is predicated.
// xor-8/16/32 reduce -> lanes 0-7 -> relu -> LDS row.  W2 column
// preloaded AFTER the reduce (8 contiguous dwordx4 from W2^T: w2r not
// live through the gather; latency hides under the barrier) ->
// __syncthreads -> in-wave gemm2 -> h2s (fp16).
__global__ __launch_bounds__(256) void k_agg12(
        const __half* __restrict__ h1s, const int* __restrict__ ents,
        const int* __restrict__ rowptr, const int* __restrict__ degi,
        const float* __restrict__ dis, const float* __restrict__ b1,
        const float* __restrict__ W2T, __half* __restrict__ h2s, int n) {
    __shared__ float h1row[4][72];
    int wid = threadIdx.x >> 6, lane = threadIdx.x & 63;
    int v = blockIdx.x * 4 + wid;
    int vc = min(v, n - 1);            // no early return (syncthreads below)
    int start = rowptr[vc], cnt = degi[vc];
    int eg = lane >> 3;
    int fq = (lane & 7) * 8;           // half-index of this lane's 8 features
    int c = lane & 31, hh = lane >> 5;
    float4 accA = {0.f, 0.f, 0.f, 0.f}, accB = accA;
    if (cnt > 0 && cnt <= 64) {
        int pre = ents[start + min(lane, cnt - 1)];
        int ng = cnt >> 3;
#pragma unroll 4
        for (int g = 0; g < ng; ++g) {
            unsigned s = ((unsigned)__shfl(pre, g * 8 + eg)) >> BSHIFT;
            h8acc(&h1s[(size_t)s * 64 + fq], accA, accB);
        }
        int rem = cnt & 7, j0 = cnt & ~7;
        if (rem) {
            unsigned s = ((unsigned)__shfl(pre, j0 + (eg < rem ? eg : 0))) >> BSHIFT;
            float4 a, b; h8load(&h1s[(size_t)s * 64 + fq], a, b);
            if (eg < rem) { f4add(accA, a); f4add(accB, b); }
        }
    } else if (cnt > 64) {
        int j = 0;
        for (; j + 8 <= cnt; j += 8) {
            unsigned s = ((unsigned)ents[start + j + eg]) >> BSHIFT;
            h8acc(&h1s[(size_t)s * 64 + fq], accA, accB);
        }
        int rem = cnt - j;
        if (rem) {
            unsigned s = ((unsigned)ents[start + j + (eg < rem ? eg : 0)]) >> BSHIFT;
            float4 a, b; h8load(&h1s[(size_t)s * 64 + fq], a, b);
            if (eg < rem) { f4add(accA, a); f4add(accB, b); }
        }
    }
    if (eg == 0) {                     // self loop
        h8acc(&h1s[(size_t)vc * 64 + fq], accA, accB);
    }
    f4red(accA, 8);  f4red(accB, 8);
    f4red(accA, 16); f4red(accB, 16);
    f4red(accA, 32); f4red(accB, 32);
    float d = dis[vc];
    if (eg == 0) {
        float4 bq0 = *(const float4*)&b1[fq];
        float4 bq1 = *(const float4*)&b1[fq + 4];
        float4 o0, o1;
        o0.x = fmaxf(fmaf(d, accA.x, bq0.x), 0.f);
        o0.y = fmaxf(fmaf(d, accA.y, bq0.y), 0.f);
        o0.z = fmaxf(fmaf(d, accA.z, bq0.z), 0.f);
        o0.w = fmaxf(fmaf(d, accA.w, bq0.w), 0.f);
        o1.x = fmaxf(fmaf(d, accB.x, bq1.x), 0.f);
        o1.y = fmaxf(fmaf(d, accB.y, bq1.y), 0.f);
        o1.z = fmaxf(fmaf(d, accB.z, bq1.z), 0.f);
        o1.w = fmaxf(fmaf(d, accB.w, bq1.w), 0.f);
        *(float4*)&h1row[wid][fq] = o0;
        *(float4*)&h1row[wid][fq + 4] = o1;
    }
    // preload W2 column c, k-range [hh*32, hh*32+32): 8 contiguous dwordx4.
    // Placed here so w2r is not live through the gather; load latency
    // overlaps the barrier wait.
    float w2r[32];
    {
        const float4* wtp = (const float4*)&W2T[(c << 6) + (hh << 5)];
#pragma unroll
        for (int q = 0; q < 8; ++q)
            *(float4*)&w2r[q * 4] = wtp[q];
    }
    __syncthreads();     // orders each wave's LDS row write before its reads
    // gemm2 in-wave: lane computes h2[c] partial over its k-half
    float p = 0.f;
#pragma unroll
    for (int j = 0; j < 32; j += 4) {
        float4 hv = *(const float4*)&h1row[wid][hh * 32 + j];
        p = fmaf(hv.x, w2r[j + 0], p);
        p = fmaf(hv.y, w2r[j + 1], p);
        p = fmaf(hv.z, w2r[j + 2], p);
        p = fmaf(hv.w, w2r[j + 3], p);
    }
    p += __shfl_xor(p, 32);
    if (hh == 0 && v < n) h2s[(size_t)v * 32 + c] = __float2half(p * d);
}

// layer-2 aggregation + relu + FC head.  fp16 row = 64 B = 4 lanes x 16 B:
// eg = lane>>2 (16 edge slots), fq = (lane&3)*8 halves; one dwordx4 covers
// 16 edges per instruction.  v_fma_mix accumulate; xor-4/8/16/32 reduce;
// FC in lanes 0-3.
__global__ void k_agg2(const __half* __restrict__ h2s, const int* __restrict__ ents,
                       const int* __restrict__ rowptr, const int* __restrict__ degi,
                       const float* __restrict__ dis, const float* __restrict__ b2,
                       const float* __restrict__ Wfc, const float* __restrict__ bfc,
                       float* __restrict__ out, int n) {
    int wid = threadIdx.x >> 6, lane = threadIdx.x & 63;
    int v = blockIdx.x * 4 + wid;
    if (v >= n) return;
    int start = rowptr[v], cnt = degi[v];
    int eg = lane >> 2;
    int fq = (lane & 3) * 8;
    float4 accA = {0.f, 0.f, 0.f, 0.f}, accB = accA;
    if (cnt > 0 && cnt <= 64) {
        int pre = ents[start + min(lane, cnt - 1)];
        int ng = cnt >> 4;
#pragma unroll 4
        for (int g = 0; g < ng; ++g) {
            unsigned s = ((unsigned)__shfl(pre, g * 16 + eg)) >> BSHIFT;
            h8acc(&h2s[(size_t)s * 32 + fq], accA, accB);
        }
        int rem = cnt & 15, j0 = cnt & ~15;
        if (rem) {
            unsigned s = ((unsigned)__shfl(pre, j0 + (eg < rem ? eg : 0))) >> BSHIFT;
            float4 a, b; h8load(&h2s[(size_t)s * 32 + fq], a, b);
            if (eg < rem) { f4add(accA, a); f4add(accB, b); }
        }
    } else if (cnt > 64) {
        int j = 0;
        for (; j + 16 <= cnt; j += 16) {
            unsigned s = ((unsigned)ents[start + j + eg]) >> BSHIFT;
            h8acc(&h2s[(size_t)s * 32 + fq], accA, accB);
        }
        int rem = cnt - j;
        if (rem) {
            unsigned s = ((unsigned)ents[start + j + (eg < rem ? eg : 0)]) >> BSHIFT;
            float4 a, b; h8load(&h2s[(size_t)s * 32 + fq], a, b);
            if (eg < rem) { f4add(accA, a); f4add(accB, b); }
        }
    }
    if (eg == 0) {                     // self loop (lanes 0-3)
        h8acc(&h2s[(size_t)v * 32 + fq], accA, accB);
    }
    f4red(accA, 4);  f4red(accB, 4);
    f4red(accA, 8);  f4red(accB, 8);
    f4red(accA, 16); f4red(accB, 16);
    f4red(accA, 32); f4red(accB, 32);
    float p = 0.f;
    if (eg == 0) {
        float d = dis[v];
        float4 bq0 = *(const float4*)&b2[fq];
        float4 bq1 = *(const float4*)&b2[fq + 4];
        float4 wq0 = *(const float4*)&Wfc[fq];
        float4 wq1 = *(const float4*)&Wfc[fq + 4];
        p  = fmaxf(fmaf(d, accA.x, bq0.x), 0.f) * wq0.x;
        p += fmaxf(fmaf(d, accA.y, bq0.y), 0.f) * wq0.y;
        p += fmaxf(fmaf(d, accA.z, bq0.z), 0.f) * wq0.z;
        p += fmaxf(fmaf(d, accA.w, bq0.w), 0.f) * wq0.w;
        p += fmaxf(fmaf(d, accB.x, bq1.x), 0.f) * wq1.x;
        p += fmaxf(fmaf(d, accB.y, bq1.y), 0.f) * wq1.y;
        p += fmaxf(fmaf(d, accB.z, bq1.z), 0.f) * wq1.z;
        p += fmaxf(fmaf(d, accB.w, bq1.w), 0.f) * wq1.w;
    }
    p += __shfl_xor(p, 1); p += __shfl_xor(p, 2);
    if (lane == 0) out[v] = p + bfc[0];
}

extern "C" void kernel_launch(void* const* d_in, const int* in_sizes, int n_in,
                              void* d_out, int out_size, void* d_ws, size_t ws_size,
                              hipStream_t stream) {
    const float* x   = (const float*)d_in[0];
    const int*   ei  = (const int*)d_in[1];
    const float* W1  = (const float*)d_in[2];
    const float* b1  = (const float*)d_in[3];
    const float* W2  = (const float*)d_in[4];
    const float* b2  = (const float*)d_in[5];
    const float* Wfc = (const float*)d_in[6];
    const float* bfc = (const float*)d_in[7];
    float* out = (float*)d_out;

    const int n = in_sizes[0] / 128;       // 100000
    const int e = in_sizes[1] / 2;         // 3200000
    const int* src = ei;
    const int* dst = ei + e;

    const int nbuck = (n + BSIZE - 1) / BSIZE;           // 782
    const int m = nbuck * B1;                            // 200192
    const int echunk = (e + B1 - 1) / B1;                // 12500

    char* p = (char*)d_ws;
    size_t off = 0;
    auto carve = [&](size_t bytes) { void* r = p + off; off = (off + bytes + 255) & ~(size_t)255; return r; };
    int*   ghist   = (int*)  carve((size_t)m * 4);
    int*   ghist_s = (int*)  carve((size_t)m * 4);
    int*   part    = (int*)  carve(256 * 4);
    float* dis     = (float*)carve((size_t)n * 4);
    int*   rowptr  = (int*)  carve((size_t)n * 4);
    int*   degi    = (int*)  carve((size_t)n * 4);
    float* W2T     = (float*)carve(2048 * 4);
    int*   ebuf2   = (int*)  carve((size_t)e * 4);
    __half* h2s    = (__half*)carve((size_t)n * 32 * 2);
    void*  ebuf_or_h1s = carve((size_t)e * 4);           // ebuf(E*4) aliases h1s(N*64*2)
    int*    ebuf = (int*)ebuf_or_h1s;
    __half* h1s  = (__half*)ebuf_or_h1s;
    (void)ws_size;

    const int nblk_scan = (m + SCAN_CHUNK - 1) / SCAN_CHUNK;   // 196 (<=256)
    const size_t lds_buck = (size_t)nbuck * 4;

    k_hist<<<B1, 256, lds_buck, stream>>>(dst, ghist, W2, W2T, e, echunk, nbuck);
    k_gscan1<<<nblk_scan, 256, 0, stream>>>(ghist, part, m);
    k_gscan2<<<nblk_scan, 256, 0, stream>>>(ghist, part, ghist_s, m, nblk_scan);
    k_binscatter<<<B1, 256, lds_buck, stream>>>(src, dst, ghist_s, ebuf, e, echunk, nbuck);
    k_csr<<<nbuck, 256, 0, stream>>>(ebuf, ghist_s, ebuf2, rowptr, degi, dis, n, e, nbuck);
    k_gemm1<<<(n + 63) / 64, 256, 0, stream>>>(x, W1, dis, h1s, n);
    k_agg12<<<(n + 3) / 4, 256, 0, stream>>>(h1s, ebuf2, rowptr, degi, dis, b1, W2T, h2s, n);
    k_agg2<<<(n + 3) / 4, 256, 0, stream>>>(h2s, ebuf2, rowptr, degi, dis, b2, Wfc, bfc, out, n);
}

// Round 9
// 305.983 us; speedup vs baseline: 2.2843x; 1.1769x over previous
//
#include <hip/hip_runtime.h>
#include <hip/hip_bf16.h>
#include <hip/hip_fp16.h>

// GCN: h = relu(GCN(x,W1,b1)); h = relu(GCN(h,W2,b2)); out = h @ Wfc + bfc
// GCN(x,W,b)[d] = dis[d] * ( sum_{(s,d) in E} hs[s] + hs[d] ) + b
//   where hs[v] = (x[v]@W) * dis[v],  dis[v] = rsqrt(1 + indeg(v))
//
// Round-24: exact revert to the round-18/round-4 form (305.2 us, best
// measured).  Attribution now complete: the W2^T per-lane-row float4
// preload (rounds 6/8) was the 2x k_agg12 regression -- each dwordx4 at
// 256-B lane stride is a 64-way cacheline scatter (512 L1 transactions
// per wave vs 64 for the scalar lane-across-column form).  The round-4
// W2 load (32 scalar loads, lanes on consecutive c) is the coalesced
// form and the compiler sinks each load to its use.  Keep: one node per
// wave, fma_mix gather accumulate, all-lane shuffles, __syncthreads.

#define SCAN_CHUNK 1024
#define BSHIFT 7
#define BSIZE 128            // dsts per bucket
#define B1 256               // blocks in hist/binscatter passes
#define CSR_CAP 5120         // max staged bucket size (avg ~4092, +5sigma ~4400)

__device__ inline void f4fma(float4& a, float s, const float4& b) {
    a.x = fmaf(s, b.x, a.x); a.y = fmaf(s, b.y, a.y);
    a.z = fmaf(s, b.z, a.z); a.w = fmaf(s, b.w, a.w);
}
__device__ inline void f4add(float4& a, const float4& b) {
    a.x += b.x; a.y += b.y; a.z += b.z; a.w += b.w;
}
__device__ inline void f4red(float4& a, int off) {
    a.x += __shfl_xor(a.x, off); a.y += __shfl_xor(a.y, off);
    a.z += __shfl_xor(a.z, off); a.w += __shfl_xor(a.w, off);
}
// 8 halves (16 B) -> two float4 (single dwordx4 load)
__device__ inline void h8load(const __half* p, float4& a, float4& b) {
    uint4 r = *(const uint4*)p;
    __half2* h = (__half2*)&r;
    float2 f0 = __half22float2(h[0]);
    float2 f1 = __half22float2(h[1]);
    float2 f2 = __half22float2(h[2]);
    float2 f3 = __half22float2(h[3]);
    a = make_float4(f0.x, f0.y, f1.x, f1.y);
    b = make_float4(f2.x, f2.y, f3.x, f3.y);
}
// acc two packed halves into two f32 accumulators: one v_fma_mix each.
// fma(cvt_f32(h), 1.0f, acc) -- exact convert, single-rounded fma ==
// bit-identical to cvt+add.
__device__ inline void hacc2(unsigned h, float& x, float& y) {
    asm("v_fma_mix_f32 %0, %2, %3, %0 op_sel:[0,0,0] op_sel_hi:[1,0,0]\n\t"
        "v_fma_mix_f32 %1, %2, %3, %1 op_sel:[1,0,0] op_sel_hi:[1,0,0]"
        : "+v"(x), "+v"(y)
        : "v"(h), "v"(1.0f));
}
// 8 halves (one dwordx4) accumulated into the 8 f32 lanes of a,b
__device__ inline void h8acc(const __half* p, float4& a, float4& b) {
    uint4 r = *(const uint4*)p;
    hacc2(r.x, a.x, a.y);
    hacc2(r.y, a.z, a.w);
    hacc2(r.z, b.x, b.y);
    hacc2(r.w, b.z, b.w);
}
__device__ inline void h4store(__half* p, float4 v) {
    __half2 a = __floats2half2_rn(v.x, v.y);
    __half2 b = __floats2half2_rn(v.z, v.w);
    uint2 r; r.x = *(uint*)&a; r.y = *(uint*)&b;
    *(uint2*)p = r;
}

// ---- generic exclusive scan (m ints, nblk = ceil(m/1024) <= 256) ----
__global__ void k_gscan1(const int* __restrict__ in, int* __restrict__ part, int m) {
    int t = threadIdx.x;
    int base = blockIdx.x * SCAN_CHUNK + t * 4;
    int s = 0;
    for (int u = 0; u < 4; ++u) { int i = base + u; if (i < m) s += in[i]; }
    for (int o = 32; o; o >>= 1) s += __shfl_down(s, o);
    __shared__ int ws[4];
    if ((t & 63) == 0) ws[t >> 6] = s;
    __syncthreads();
    if (t == 0) part[blockIdx.x] = ws[0] + ws[1] + ws[2] + ws[3];
}

__global__ void k_gscan2(const int* __restrict__ in, const int* __restrict__ part,
                         int* __restrict__ out, int m, int nblk) {
    int t = threadIdx.x;
    int b = blockIdx.x;
    int pv = (t < b && t < nblk) ? part[t] : 0;
    int ps = pv;
    for (int o = 32; o; o >>= 1) ps += __shfl_down(ps, o);
    __shared__ int sh[4];
    if ((t & 63) == 0) sh[t >> 6] = ps;
    __syncthreads();
    int blockoff = sh[0] + sh[1] + sh[2] + sh[3];

    int base = b * SCAN_CHUNK + t * 4;
    int v0 = 0, v1 = 0, v2 = 0, v3 = 0;
    if (base + 0 < m) v0 = in[base + 0];
    if (base + 1 < m) v1 = in[base + 1];
    if (base + 2 < m) v2 = in[base + 2];
    if (base + 3 < m) v3 = in[base + 3];
    int tot = v0 + v1 + v2 + v3;
    int lane = t & 63, wid = t >> 6;
    int incl = tot;
    for (int o = 1; o < 64; o <<= 1) { int u = __shfl_up(incl, o); if (lane >= o) incl += u; }
    int excl = incl - tot;
    __shared__ int wt[4];
    if (lane == 63) wt[wid] = incl;
    __syncthreads();
    int woff = 0;
    for (int w = 0; w < wid; ++w) woff += wt[w];
    int off = blockoff + woff + excl;
    if (base + 0 < m) out[base + 0] = off;
    if (base + 1 < m) out[base + 1] = off + v0;
    if (base + 2 < m) out[base + 2] = off + v0 + v1;
    if (base + 3 < m) out[base + 3] = off + v0 + v1 + v2;
}

// ---- pass 1a: per-block bucket histogram (LDS atomics, int4 reads) ----
__global__ __launch_bounds__(256) void k_hist(const int* __restrict__ dst,
                                              int* __restrict__ ghist,
                                              int e, int echunk, int nbuck) {
    extern __shared__ int h[];   // nbuck ints
    int t = threadIdx.x, b = blockIdx.x;
    for (int i = t; i < nbuck; i += 256) h[i] = 0;
    __syncthreads();
    int s = b * echunk, epd = min(e, s + echunk);
    for (int i = s + t * 4; i < epd; i += 1024) {
        if (i + 3 < epd) {
            int4 d4 = *(const int4*)&dst[i];
            atomicAdd(&h[d4.x >> BSHIFT], 1);
            atomicAdd(&h[d4.y >> BSHIFT], 1);
            atomicAdd(&h[d4.z >> BSHIFT], 1);
            atomicAdd(&h[d4.w >> BSHIFT], 1);
        } else {
            for (int u = i; u < epd; ++u) atomicAdd(&h[dst[u] >> BSHIFT], 1);
        }
    }
    __syncthreads();
    for (int k = t; k < nbuck; k += 256)
        ghist[k * B1 + b] = h[k];
}

// ---- pass 1b: scatter packed (src<<7|dlow) into bucket-ordered ebuf ----
__global__ __launch_bounds__(256) void k_binscatter(
        const int* __restrict__ src, const int* __restrict__ dst,
        const int* __restrict__ ghist_s, int* __restrict__ ebuf,
        int e, int echunk, int nbuck) {
    extern __shared__ int cur[];   // nbuck ints
    int t = threadIdx.x, b = blockIdx.x;
    for (int k = t; k < nbuck; k += 256)
        cur[k] = ghist_s[k * B1 + b];
    __syncthreads();
    int s = b * echunk, epd = min(e, s + echunk);
    for (int i = s + t * 4; i < epd; i += 1024) {
        if (i + 3 < epd) {
            int4 d4 = *(const int4*)&dst[i];
            int4 s4 = *(const int4*)&src[i];
            int p0 = atomicAdd(&cur[d4.x >> BSHIFT], 1);
            int p1 = atomicAdd(&cur[d4.y >> BSHIFT], 1);
            int p2 = atomicAdd(&cur[d4.z >> BSHIFT], 1);
            int p3 = atomicAdd(&cur[d4.w >> BSHIFT], 1);
            ebuf[p0] = (s4.x << BSHIFT) | (d4.x & (BSIZE - 1));
            ebuf[p1] = (s4.y << BSHIFT) | (d4.y & (BSIZE - 1));
            ebuf[p2] = (s4.z << BSHIFT) | (d4.z & (BSIZE - 1));
            ebuf[p3] = (s4.w << BSHIFT) | (d4.w & (BSIZE - 1));
        } else {
            for (int u = i; u < epd; ++u) {
                int d = dst[u];
                int pos = atomicAdd(&cur[d >> BSHIFT], 1);
                ebuf[pos] = (src[u] << BSHIFT) | (d & (BSIZE - 1));
            }
        }
    }
}

// ---- pass 2: per-bucket dst counting sort -> ebuf2 (bucket-local CSR) ----
__global__ __launch_bounds__(256) void k_csr(
        const int* __restrict__ ebuf, const int* __restrict__ ghist_s,
        int* __restrict__ ebuf2, int* __restrict__ rowptr, int* __restrict__ degi,
        float* __restrict__ dis, int n, int e, int nbuck) {
    int k = blockIdx.x, t = threadIdx.x;
    int estart = ghist_s[k * B1];
    int eend = (k + 1 < nbuck) ? ghist_s[(k + 1) * B1] : e;
    int ecnt = eend - estart;
    __shared__ int ein[CSR_CAP];
    __shared__ int eout[CSR_CAP];
    __shared__ int cnt[BSIZE];
    __shared__ int cur[BSIZE];
    __shared__ int wt[4];
    if (t < BSIZE) cnt[t] = 0;
    bool staged = (ecnt <= CSR_CAP);
    if (staged) {
        for (int i = t; i < ecnt; i += 256) ein[i] = ebuf[estart + i];
    }
    __syncthreads();
    if (staged) {
        for (int i = t; i < ecnt; i += 256)
            atomicAdd(&cnt[ein[i] & (BSIZE - 1)], 1);
    } else {
        for (int i = estart + t; i < eend; i += 256)
            atomicAdd(&cnt[ebuf[i] & (BSIZE - 1)], 1);
    }
    __syncthreads();
    int v = (t < BSIZE) ? cnt[t] : 0;
    int lane = t & 63, wid = t >> 6;
    int incl = v;
    for (int o = 1; o < 64; o <<= 1) { int u = __shfl_up(incl, o); if (lane >= o) incl += u; }
    if (lane == 63) wt[wid] = incl;
    __syncthreads();
    int woff = (wid == 1) ? wt[0] : 0;
    int excl = woff + incl - v;
    if (t < BSIZE) {
        cur[t] = excl;                       // bucket-local offset
        int node = k * BSIZE + t;
        if (node < n) {
            rowptr[node] = estart + excl;
            degi[node]   = v;
            dis[node]    = rsqrtf((float)(v + 1));
        }
    }
    __syncthreads();
    if (staged) {
        for (int i = t; i < ecnt; i += 256) {
            int w = ein[i];
            int pos = atomicAdd(&cur[w & (BSIZE - 1)], 1);
            eout[pos] = w;                   // scatter stays in LDS
        }
        __syncthreads();
        for (int i = t; i < ecnt; i += 256)  // coalesced write-out
            ebuf2[estart + i] = eout[i];
    } else {
        for (int i = estart + t; i < eend; i += 256) {
            int w = ebuf[i];
            int pos = estart + atomicAdd(&cur[w & (BSIZE - 1)], 1);
            ebuf2[pos] = w;
        }
    }
}

// h1s = fp16( (x @ W1) * dis ) — outer-product GEMM, block tile 64x64, K=128.
#define SA 132
__global__ __launch_bounds__(256) void k_gemm1(
        const float* __restrict__ x, const float* __restrict__ W1,
        const float* __restrict__ dis, __half* __restrict__ h1s, int n) {
    __shared__ float Xs[64 * SA];    // 33 KB
    __shared__ float Ws[128 * 64];   // 32 KB
    int t = threadIdx.x;
    int nbase = blockIdx.x * 64;
    for (int i = t; i < 2048; i += 256)
        ((float4*)Ws)[i] = ((const float4*)W1)[i];
    for (int i = t; i < 2048; i += 256) {
        int row = i >> 5, q = i & 31;
        int r = nbase + row; if (r >= n) r = n - 1;
        float4 v = ((const float4*)(x + (size_t)r * 128))[q];
        *(float4*)&Xs[row * SA + q * 4] = v;
    }
    __syncthreads();
    int wid = t >> 6, lane = t & 63;
    int lx = lane & 7, ly = lane >> 3;
    int wm = wid & 1, wn = wid >> 1;
    int row0 = wm * 32 + ly * 4;
    int col0 = wn * 32 + lx * 4;
    float4 acc0 = {0.f,0.f,0.f,0.f}, acc1 = acc0, acc2 = acc0, acc3 = acc0;
#pragma unroll 4
    for (int k4 = 0; k4 < 32; ++k4) {
        int k = k4 * 4;
        float4 a0 = *(const float4*)&Xs[(row0 + 0) * SA + k];
        float4 a1 = *(const float4*)&Xs[(row0 + 1) * SA + k];
        float4 a2 = *(const float4*)&Xs[(row0 + 2) * SA + k];
        float4 a3 = *(const float4*)&Xs[(row0 + 3) * SA + k];
        float4 b0 = *(const float4*)&Ws[(k + 0) * 64 + col0];
        float4 b1 = *(const float4*)&Ws[(k + 1) * 64 + col0];
        float4 b2 = *(const float4*)&Ws[(k + 2) * 64 + col0];
        float4 b3 = *(const float4*)&Ws[(k + 3) * 64 + col0];
        f4fma(acc0, a0.x, b0); f4fma(acc0, a0.y, b1); f4fma(acc0, a0.z, b2); f4fma(acc0, a0.w, b3);
        f4fma(acc1, a1.x, b0); f4fma(acc1, a1.y, b1); f4fma(acc1, a1.z, b2); f4fma(acc1, a1.w, b3);
        f4fma(acc2, a2.x, b0); f4fma(acc2, a2.y, b1); f4fma(acc2, a2.z, b2); f4fma(acc2, a2.w, b3);
        f4fma(acc3, a3.x, b0); f4fma(acc3, a3.y, b1); f4fma(acc3, a3.z, b2); f4fma(acc3, a3.w, b3);
    }
    int grow = nbase + row0;
#pragma unroll
    for (int r = 0; r < 4; ++r) {
        int rr = grow + r;
        if (rr < n) {
            float d = dis[rr];
            float4 o = (r == 0) ? acc0 : (r == 1) ? acc1 : (r == 2) ? acc2 : acc3;
            o.x *= d; o.y *= d; o.z *= d; o.w *= d;
            h4store(&h1s[(size_t)rr * 64 + col0], o);
        }
    }
}

// Layer-1 aggregation + relu/b1 + gemm2, fused (round-4 shape: one node
// per wave, 25K blocks, W2 column in 32 VGPRs via coalesced scalar
// global loads -- lanes c=0..31 on consecutive addresses; the compiler
// sinks each load to its single use in the gemm2 loop).  fp16 row =
// 128 B = 8 lanes x 16 B: eg = lane>>3 (8 edge slots), fq = (lane&7)*8;
// one dwordx4 covers 8 edges.  v_fma_mix accumulate.  Shuffles all-lane
// (ds_bpermute from an inactive lane is undefined); only the add is
// predicated.  xor-8/16/32 reduce -> lanes 0-7 -> relu -> LDS row ->
// __syncthreads -> in-wave gemm2 -> h2s (fp16).
__global__ __launch_bounds__(256) void k_agg12(
        const __half* __restrict__ h1s, const int* __restrict__ ents,
        const int* __restrict__ rowptr, const int* __restrict__ degi,
        const float* __restrict__ dis, const float* __restrict__ b1,
        const float* __restrict__ W2, __half* __restrict__ h2s, int n) {
    __shared__ float h1row[4][72];
    int wid = threadIdx.x >> 6, lane = threadIdx.x & 63;
    int v = blockIdx.x * 4 + wid;
    int vc = min(v, n - 1);            // no early return (syncthreads below)
    int start = rowptr[vc], cnt = degi[vc];
    int eg = lane >> 3;
    int fq = (lane & 7) * 8;           // half-index of this lane's 8 features
    int c = lane & 31, hh = lane >> 5;
    // preload W2 column c, k-range [hh*32, hh*32+32) -> 32 VGPRs
    float w2r[32];
#pragma unroll
    for (int j = 0; j < 32; ++j)
        w2r[j] = W2[(hh * 32 + j) * 32 + c];
    float4 accA = {0.f, 0.f, 0.f, 0.f}, accB = accA;
    if (cnt > 0 && cnt <= 64) {
        int pre = ents[start + min(lane, cnt - 1)];
        int ng = cnt >> 3;
#pragma unroll 4
        for (int g = 0; g < ng; ++g) {
            unsigned s = ((unsigned)__shfl(pre, g * 8 + eg)) >> BSHIFT;
            h8acc(&h1s[(size_t)s * 64 + fq], accA, accB);
        }
        int rem = cnt & 7, j0 = cnt & ~7;
        if (rem) {
            unsigned s = ((unsigned)__shfl(pre, j0 + (eg < rem ? eg : 0))) >> BSHIFT;
            float4 a, b; h8load(&h1s[(size_t)s * 64 + fq], a, b);
            if (eg < rem) { f4add(accA, a); f4add(accB, b); }
        }
    } else if (cnt > 64) {
        int j = 0;
        for (; j + 8 <= cnt; j += 8) {
            unsigned s = ((unsigned)ents[start + j + eg]) >> BSHIFT;
            h8acc(&h1s[(size_t)s * 64 + fq], accA, accB);
        }
        int rem = cnt - j;
        if (rem) {
            unsigned s = ((unsigned)ents[start + j + (eg < rem ? eg : 0)]) >> BSHIFT;
            float4 a, b; h8load(&h1s[(size_t)s * 64 + fq], a, b);
            if (eg < rem) { f4add(accA, a); f4add(accB, b); }
        }
    }
    if (eg == 0) {                     // self loop
        h8acc(&h1s[(size_t)vc * 64 + fq], accA, accB);
    }
    f4red(accA, 8);  f4red(accB, 8);
    f4red(accA, 16); f4red(accB, 16);
    f4red(accA, 32); f4red(accB, 32);
    float d = dis[vc];
    if (eg == 0) {
        float4 bq0 = *(const float4*)&b1[fq];
        float4 bq1 = *(const float4*)&b1[fq + 4];
        float4 o0, o1;
        o0.x = fmaxf(fmaf(d, accA.x, bq0.x), 0.f);
        o0.y = fmaxf(fmaf(d, accA.y, bq0.y), 0.f);
        o0.z = fmaxf(fmaf(d, accA.z, bq0.z), 0.f);
        o0.w = fmaxf(fmaf(d, accA.w, bq0.w), 0.f);
        o1.x = fmaxf(fmaf(d, accB.x, bq1.x), 0.f);
        o1.y = fmaxf(fmaf(d, accB.y, bq1.y), 0.f);
        o1.z = fmaxf(fmaf(d, accB.z, bq1.z), 0.f);
        o1.w = fmaxf(fmaf(d, accB.w, bq1.w), 0.f);
        *(float4*)&h1row[wid][fq] = o0;
        *(float4*)&h1row[wid][fq + 4] = o1;
    }
    __syncthreads();     // orders each wave's LDS row write before its reads
    // gemm2 in-wave: lane computes h2[c] partial over its k-half
    float p = 0.f;
#pragma unroll
    for (int j = 0; j < 32; j += 4) {
        float4 hv = *(const float4*)&h1row[wid][hh * 32 + j];
        p = fmaf(hv.x, w2r[j + 0], p);
        p = fmaf(hv.y, w2r[j + 1], p);
        p = fmaf(hv.z, w2r[j + 2], p);
        p = fmaf(hv.w, w2r[j + 3], p);
    }
    p += __shfl_xor(p, 32);
    if (hh == 0 && v < n) h2s[(size_t)v * 32 + c] = __float2half(p * d);
}

// layer-2 aggregation + relu + FC head.  fp16 row = 64 B = 4 lanes x 16 B:
// eg = lane>>2 (16 edge slots), fq = (lane&3)*8 halves; one dwordx4 covers
// 16 edges per instruction.  v_fma_mix accumulate; xor-4/8/16/32 reduce;
// FC in lanes 0-3.
__global__ void k_agg2(const __half* __restrict__ h2s, const int* __restrict__ ents,
                       const int* __restrict__ rowptr, const int* __restrict__ degi,
                       const float* __restrict__ dis, const float* __restrict__ b2,
                       const float* __restrict__ Wfc, const float* __restrict__ bfc,
                       float* __restrict__ out, int n) {
    int wid = threadIdx.x >> 6, lane = threadIdx.x & 63;
    int v = blockIdx.x * 4 + wid;
    if (v >= n) return;
    int start = rowptr[v], cnt = degi[v];
    int eg = lane >> 2;
    int fq = (lane & 3) * 8;
    float4 accA = {0.f, 0.f, 0.f, 0.f}, accB = accA;
    if (cnt > 0 && cnt <= 64) {
        int pre = ents[start + min(lane, cnt - 1)];
        int ng = cnt >> 4;
#pragma unroll 4
        for (int g = 0; g < ng; ++g) {
            unsigned s = ((unsigned)__shfl(pre, g * 16 + eg)) >> BSHIFT;
            h8acc(&h2s[(size_t)s * 32 + fq], accA, accB);
        }
        int rem = cnt & 15, j0 = cnt & ~15;
        if (rem) {
            unsigned s = ((unsigned)__shfl(pre, j0 + (eg < rem ? eg : 0))) >> BSHIFT;
            float4 a, b; h8load(&h2s[(size_t)s * 32 + fq], a, b);
            if (eg < rem) { f4add(accA, a); f4add(accB, b); }
        }
    } else if (cnt > 64) {
        int j = 0;
        for (; j + 16 <= cnt; j += 16) {
            unsigned s = ((unsigned)ents[start + j + eg]) >> BSHIFT;
            h8acc(&h2s[(size_t)s * 32 + fq], accA, accB);
        }
        int rem = cnt - j;
        if (rem) {
            unsigned s = ((unsigned)ents[start + j + (eg < rem ? eg : 0)]) >> BSHIFT;
            float4 a, b; h8load(&h2s[(size_t)s * 32 + fq], a, b);
            if (eg < rem) { f4add(accA, a); f4add(accB, b); }
        }
    }
    if (eg == 0) {                     // self loop (lanes 0-3)
        h8acc(&h2s[(size_t)v * 32 + fq], accA, accB);
    }
    f4red(accA, 4);  f4red(accB, 4);
    f4red(accA, 8);  f4red(accB, 8);
    f4red(accA, 16); f4red(accB, 16);
    f4red(accA, 32); f4red(accB, 32);
    float p = 0.f;
    if (eg == 0) {
        float d = dis[v];
        float4 bq0 = *(const float4*)&b2[fq];
        float4 bq1 = *(const float4*)&b2[fq + 4];
        float4 wq0 = *(const float4*)&Wfc[fq];
        float4 wq1 = *(const float4*)&Wfc[fq + 4];
        p  = fmaxf(fmaf(d, accA.x, bq0.x), 0.f) * wq0.x;
        p += fmaxf(fmaf(d, accA.y, bq0.y), 0.f) * wq0.y;
        p += fmaxf(fmaf(d, accA.z, bq0.z), 0.f) * wq0.z;
        p += fmaxf(fmaf(d, accA.w, bq0.w), 0.f) * wq0.w;
        p += fmaxf(fmaf(d, accB.x, bq1.x), 0.f) * wq1.x;
        p += fmaxf(fmaf(d, accB.y, bq1.y), 0.f) * wq1.y;
        p += fmaxf(fmaf(d, accB.z, bq1.z), 0.f) * wq1.z;
        p += fmaxf(fmaf(d, accB.w, bq1.w), 0.f) * wq1.w;
    }
    p += __shfl_xor(p, 1); p += __shfl_xor(p, 2);
    if (lane == 0) out[v] = p + bfc[0];
}

extern "C" void kernel_launch(void* const* d_in, const int* in_sizes, int n_in,
                              void* d_out, int out_size, void* d_ws, size_t ws_size,
                              hipStream_t stream) {
    const float* x   = (const float*)d_in[0];
    const int*   ei  = (const int*)d_in[1];
    const float* W1  = (const float*)d_in[2];
    const float* b1  = (const float*)d_in[3];
    const float* W2  = (const float*)d_in[4];
    const float* b2  = (const float*)d_in[5];
    const float* Wfc = (const float*)d_in[6];
    const float* bfc = (const float*)d_in[7];
    float* out = (float*)d_out;

    const int n = in_sizes[0] / 128;       // 100000
    const int e = in_sizes[1] / 2;         // 3200000
    const int* src = ei;
    const int* dst = ei + e;

    const int nbuck = (n + BSIZE - 1) / BSIZE;           // 782
    const int m = nbuck * B1;                            // 200192
    const int echunk = (e + B1 - 1) / B1;                // 12500

    char* p = (char*)d_ws;
    size_t off = 0;
    auto carve = [&](size_t bytes) { void* r = p + off; off = (off + bytes + 255) & ~(size_t)255; return r; };
    int*   ghist   = (int*)  carve((size_t)m * 4);
    int*   ghist_s = (int*)  carve((size_t)m * 4);
    int*   part    = (int*)  carve(256 * 4);
    float* dis     = (float*)carve((size_t)n * 4);
    int*   rowptr  = (int*)  carve((size_t)n * 4);
    int*   degi    = (int*)  carve((size_t)n * 4);
    int*   ebuf2   = (int*)  carve((size_t)e * 4);
    __half* h2s    = (__half*)carve((size_t)n * 32 * 2);
    void*  ebuf_or_h1s = carve((size_t)e * 4);           // ebuf(E*4) aliases h1s(N*64*2)
    int*    ebuf = (int*)ebuf_or_h1s;
    __half* h1s  = (__half*)ebuf_or_h1s;
    (void)ws_size;

    const int nblk_scan = (m + SCAN_CHUNK - 1) / SCAN_CHUNK;   // 196 (<=256)
    const size_t lds_buck = (size_t)nbuck * 4;

    k_hist<<<B1, 256, lds_buck, stream>>>(dst, ghist, e, echunk, nbuck);
    k_gscan1<<<nblk_scan, 256, 0, stream>>>(ghist, part, m);
    k_gscan2<<<nblk_scan, 256, 0, stream>>>(ghist, part, ghist_s, m, nblk_scan);
    k_binscatter<<<B1, 256, lds_buck, stream>>>(src, dst, ghist_s, ebuf, e, echunk, nbuck);
    k_csr<<<nbuck, 256, 0, stream>>>(ebuf, ghist_s, ebuf2, rowptr, degi, dis, n, e, nbuck);
    k_gemm1<<<(n + 63) / 64, 256, 0, stream>>>(x, W1, dis, h1s, n);
    k_agg12<<<(n + 3) / 4, 256, 0, stream>>>(h1s, ebuf2, rowptr, degi, dis, b1, W2, h2s, n);
    k_agg2<<<(n + 3) / 4, 256, 0, stream>>>(h2s, ebuf2, rowptr, degi, dis, b2, Wfc, bfc, out, n);
}

// Round 10
// 302.146 us; speedup vs baseline: 2.3133x; 1.0127x over previous
//
#include <hip/hip_runtime.h>
#include <hip/hip_bf16.h>
#include <hip/hip_fp16.h>

// GCN: h = relu(GCN(x,W1,b1)); h = relu(GCN(h,W2,b2)); out = h @ Wfc + bfc
// GCN(x,W,b)[d] = dis[d] * ( sum_{(s,d) in E} hs[s] + hs[d] ) + b
//   where hs[v] = (x[v]@W) * dis[v],  dis[v] = rsqrt(1 + indeg(v))
//
// Round-25: baseline (305.2/306.0, proven 3x) + two latency-targeted
// tweaks.  k_agg12 is ~80% memory-wait (issue floor ~16 us vs 74.6
// measured); Little's-law says in-flight bytes/CU ~= the unroll-4 window.
// (1) unroll 8 on the cnt<=64 gather (full unroll of ng<=8): doubles the
//     per-wave load window.  Diagnostic: no change => per-CU cap.
// (2) (rowptr,degi) packed into one int2 meta array: one 8-B load
//     replaces two 4-B loads on each wave's critical-path preamble.

#define SCAN_CHUNK 1024
#define BSHIFT 7
#define BSIZE 128            // dsts per bucket
#define B1 256               // blocks in hist/binscatter passes
#define CSR_CAP 5120         // max staged bucket size (avg ~4092, +5sigma ~4400)

__device__ inline void f4fma(float4& a, float s, const float4& b) {
    a.x = fmaf(s, b.x, a.x); a.y = fmaf(s, b.y, a.y);
    a.z = fmaf(s, b.z, a.z); a.w = fmaf(s, b.w, a.w);
}
__device__ inline void f4add(float4& a, const float4& b) {
    a.x += b.x; a.y += b.y; a.z += b.z; a.w += b.w;
}
__device__ inline void f4red(float4& a, int off) {
    a.x += __shfl_xor(a.x, off); a.y += __shfl_xor(a.y, off);
    a.z += __shfl_xor(a.z, off); a.w += __shfl_xor(a.w, off);
}
// 8 halves (16 B) -> two float4 (single dwordx4 load)
__device__ inline void h8load(const __half* p, float4& a, float4& b) {
    uint4 r = *(const uint4*)p;
    __half2* h = (__half2*)&r;
    float2 f0 = __half22float2(h[0]);
    float2 f1 = __half22float2(h[1]);
    float2 f2 = __half22float2(h[2]);
    float2 f3 = __half22float2(h[3]);
    a = make_float4(f0.x, f0.y, f1.x, f1.y);
    b = make_float4(f2.x, f2.y, f3.x, f3.y);
}
// acc two packed halves into two f32 accumulators: one v_fma_mix each.
// fma(cvt_f32(h), 1.0f, acc) -- exact convert, single-rounded fma ==
// bit-identical to cvt+add.
__device__ inline void hacc2(unsigned h, float& x, float& y) {
    asm("v_fma_mix_f32 %0, %2, %3, %0 op_sel:[0,0,0] op_sel_hi:[1,0,0]\n\t"
        "v_fma_mix_f32 %1, %2, %3, %1 op_sel:[1,0,0] op_sel_hi:[1,0,0]"
        : "+v"(x), "+v"(y)
        : "v"(h), "v"(1.0f));
}
// 8 halves (one dwordx4) accumulated into the 8 f32 lanes of a,b
__device__ inline void h8acc(const __half* p, float4& a, float4& b) {
    uint4 r = *(const uint4*)p;
    hacc2(r.x, a.x, a.y);
    hacc2(r.y, a.z, a.w);
    hacc2(r.z, b.x, b.y);
    hacc2(r.w, b.z, b.w);
}
__device__ inline void h4store(__half* p, float4 v) {
    __half2 a = __floats2half2_rn(v.x, v.y);
    __half2 b = __floats2half2_rn(v.z, v.w);
    uint2 r; r.x = *(uint*)&a; r.y = *(uint*)&b;
    *(uint2*)p = r;
}

// ---- generic exclusive scan (m ints, nblk = ceil(m/1024) <= 256) ----
__global__ void k_gscan1(const int* __restrict__ in, int* __restrict__ part, int m) {
    int t = threadIdx.x;
    int base = blockIdx.x * SCAN_CHUNK + t * 4;
    int s = 0;
    for (int u = 0; u < 4; ++u) { int i = base + u; if (i < m) s += in[i]; }
    for (int o = 32; o; o >>= 1) s += __shfl_down(s, o);
    __shared__ int ws[4];
    if ((t & 63) == 0) ws[t >> 6] = s;
    __syncthreads();
    if (t == 0) part[blockIdx.x] = ws[0] + ws[1] + ws[2] + ws[3];
}

__global__ void k_gscan2(const int* __restrict__ in, const int* __restrict__ part,
                         int* __restrict__ out, int m, int nblk) {
    int t = threadIdx.x;
    int b = blockIdx.x;
    int pv = (t < b && t < nblk) ? part[t] : 0;
    int ps = pv;
    for (int o = 32; o; o >>= 1) ps += __shfl_down(ps, o);
    __shared__ int sh[4];
    if ((t & 63) == 0) sh[t >> 6] = ps;
    __syncthreads();
    int blockoff = sh[0] + sh[1] + sh[2] + sh[3];

    int base = b * SCAN_CHUNK + t * 4;
    int v0 = 0, v1 = 0, v2 = 0, v3 = 0;
    if (base + 0 < m) v0 = in[base + 0];
    if (base + 1 < m) v1 = in[base + 1];
    if (base + 2 < m) v2 = in[base + 2];
    if (base + 3 < m) v3 = in[base + 3];
    int tot = v0 + v1 + v2 + v3;
    int lane = t & 63, wid = t >> 6;
    int incl = tot;
    for (int o = 1; o < 64; o <<= 1) { int u = __shfl_up(incl, o); if (lane >= o) incl += u; }
    int excl = incl - tot;
    __shared__ int wt[4];
    if (lane == 63) wt[wid] = incl;
    __syncthreads();
    int woff = 0;
    for (int w = 0; w < wid; ++w) woff += wt[w];
    int off = blockoff + woff + excl;
    if (base + 0 < m) out[base + 0] = off;
    if (base + 1 < m) out[base + 1] = off + v0;
    if (base + 2 < m) out[base + 2] = off + v0 + v1;
    if (base + 3 < m) out[base + 3] = off + v0 + v1 + v2;
}

// ---- pass 1a: per-block bucket histogram (LDS atomics, int4 reads) ----
__global__ __launch_bounds__(256) void k_hist(const int* __restrict__ dst,
                                              int* __restrict__ ghist,
                                              int e, int echunk, int nbuck) {
    extern __shared__ int h[];   // nbuck ints
    int t = threadIdx.x, b = blockIdx.x;
    for (int i = t; i < nbuck; i += 256) h[i] = 0;
    __syncthreads();
    int s = b * echunk, epd = min(e, s + echunk);
    for (int i = s + t * 4; i < epd; i += 1024) {
        if (i + 3 < epd) {
            int4 d4 = *(const int4*)&dst[i];
            atomicAdd(&h[d4.x >> BSHIFT], 1);
            atomicAdd(&h[d4.y >> BSHIFT], 1);
            atomicAdd(&h[d4.z >> BSHIFT], 1);
            atomicAdd(&h[d4.w >> BSHIFT], 1);
        } else {
            for (int u = i; u < epd; ++u) atomicAdd(&h[dst[u] >> BSHIFT], 1);
        }
    }
    __syncthreads();
    for (int k = t; k < nbuck; k += 256)
        ghist[k * B1 + b] = h[k];
}

// ---- pass 1b: scatter packed (src<<7|dlow) into bucket-ordered ebuf ----
__global__ __launch_bounds__(256) void k_binscatter(
        const int* __restrict__ src, const int* __restrict__ dst,
        const int* __restrict__ ghist_s, int* __restrict__ ebuf,
        int e, int echunk, int nbuck) {
    extern __shared__ int cur[];   // nbuck ints
    int t = threadIdx.x, b = blockIdx.x;
    for (int k = t; k < nbuck; k += 256)
        cur[k] = ghist_s[k * B1 + b];
    __syncthreads();
    int s = b * echunk, epd = min(e, s + echunk);
    for (int i = s + t * 4; i < epd; i += 1024) {
        if (i + 3 < epd) {
            int4 d4 = *(const int4*)&dst[i];
            int4 s4 = *(const int4*)&src[i];
            int p0 = atomicAdd(&cur[d4.x >> BSHIFT], 1);
            int p1 = atomicAdd(&cur[d4.y >> BSHIFT], 1);
            int p2 = atomicAdd(&cur[d4.z >> BSHIFT], 1);
            int p3 = atomicAdd(&cur[d4.w >> BSHIFT], 1);
            ebuf[p0] = (s4.x << BSHIFT) | (d4.x & (BSIZE - 1));
            ebuf[p1] = (s4.y << BSHIFT) | (d4.y & (BSIZE - 1));
            ebuf[p2] = (s4.z << BSHIFT) | (d4.z & (BSIZE - 1));
            ebuf[p3] = (s4.w << BSHIFT) | (d4.w & (BSIZE - 1));
        } else {
            for (int u = i; u < epd; ++u) {
                int d = dst[u];
                int pos = atomicAdd(&cur[d >> BSHIFT], 1);
                ebuf[pos] = (src[u] << BSHIFT) | (d & (BSIZE - 1));
            }
        }
    }
}

// ---- pass 2: per-bucket dst counting sort -> ebuf2 (bucket-local CSR) ----
// emits meta[node] = (rowstart, deg) packed int2 + dis.
__global__ __launch_bounds__(256) void k_csr(
        const int* __restrict__ ebuf, const int* __restrict__ ghist_s,
        int* __restrict__ ebuf2, int2* __restrict__ meta,
        float* __restrict__ dis, int n, int e, int nbuck) {
    int k = blockIdx.x, t = threadIdx.x;
    int estart = ghist_s[k * B1];
    int eend = (k + 1 < nbuck) ? ghist_s[(k + 1) * B1] : e;
    int ecnt = eend - estart;
    __shared__ int ein[CSR_CAP];
    __shared__ int eout[CSR_CAP];
    __shared__ int cnt[BSIZE];
    __shared__ int cur[BSIZE];
    __shared__ int wt[4];
    if (t < BSIZE) cnt[t] = 0;
    bool staged = (ecnt <= CSR_CAP);
    if (staged) {
        for (int i = t; i < ecnt; i += 256) ein[i] = ebuf[estart + i];
    }
    __syncthreads();
    if (staged) {
        for (int i = t; i < ecnt; i += 256)
            atomicAdd(&cnt[ein[i] & (BSIZE - 1)], 1);
    } else {
        for (int i = estart + t; i < eend; i += 256)
            atomicAdd(&cnt[ebuf[i] & (BSIZE - 1)], 1);
    }
    __syncthreads();
    int v = (t < BSIZE) ? cnt[t] : 0;
    int lane = t & 63, wid = t >> 6;
    int incl = v;
    for (int o = 1; o < 64; o <<= 1) { int u = __shfl_up(incl, o); if (lane >= o) incl += u; }
    if (lane == 63) wt[wid] = incl;
    __syncthreads();
    int woff = (wid == 1) ? wt[0] : 0;
    int excl = woff + incl - v;
    if (t < BSIZE) {
        cur[t] = excl;                       // bucket-local offset
        int node = k * BSIZE + t;
        if (node < n) {
            meta[node] = make_int2(estart + excl, v);
            dis[node]  = rsqrtf((float)(v + 1));
        }
    }
    __syncthreads();
    if (staged) {
        for (int i = t; i < ecnt; i += 256) {
            int w = ein[i];
            int pos = atomicAdd(&cur[w & (BSIZE - 1)], 1);
            eout[pos] = w;                   // scatter stays in LDS
        }
        __syncthreads();
        for (int i = t; i < ecnt; i += 256)  // coalesced write-out
            ebuf2[estart + i] = eout[i];
    } else {
        for (int i = estart + t; i < eend; i += 256) {
            int w = ebuf[i];
            int pos = estart + atomicAdd(&cur[w & (BSIZE - 1)], 1);
            ebuf2[pos] = w;
        }
    }
}

// h1s = fp16( (x @ W1) * dis ) — outer-product GEMM, block tile 64x64, K=128.
#define SA 132
__global__ __launch_bounds__(256) void k_gemm1(
        const float* __restrict__ x, const float* __restrict__ W1,
        const float* __restrict__ dis, __half* __restrict__ h1s, int n) {
    __shared__ float Xs[64 * SA];    // 33 KB
    __shared__ float Ws[128 * 64];   // 32 KB
    int t = threadIdx.x;
    int nbase = blockIdx.x * 64;
    for (int i = t; i < 2048; i += 256)
        ((float4*)Ws)[i] = ((const float4*)W1)[i];
    for (int i = t; i < 2048; i += 256) {
        int row = i >> 5, q = i & 31;
        int r = nbase + row; if (r >= n) r = n - 1;
        float4 v = ((const float4*)(x + (size_t)r * 128))[q];
        *(float4*)&Xs[row * SA + q * 4] = v;
    }
    __syncthreads();
    int wid = t >> 6, lane = t & 63;
    int lx = lane & 7, ly = lane >> 3;
    int wm = wid & 1, wn = wid >> 1;
    int row0 = wm * 32 + ly * 4;
    int col0 = wn * 32 + lx * 4;
    float4 acc0 = {0.f,0.f,0.f,0.f}, acc1 = acc0, acc2 = acc0, acc3 = acc0;
#pragma unroll 4
    for (int k4 = 0; k4 < 32; ++k4) {
        int k = k4 * 4;
        float4 a0 = *(const float4*)&Xs[(row0 + 0) * SA + k];
        float4 a1 = *(const float4*)&Xs[(row0 + 1) * SA + k];
        float4 a2 = *(const float4*)&Xs[(row0 + 2) * SA + k];
        float4 a3 = *(const float4*)&Xs[(row0 + 3) * SA + k];
        float4 b0 = *(const float4*)&Ws[(k + 0) * 64 + col0];
        float4 b1 = *(const float4*)&Ws[(k + 1) * 64 + col0];
        float4 b2 = *(const float4*)&Ws[(k + 2) * 64 + col0];
        float4 b3 = *(const float4*)&Ws[(k + 3) * 64 + col0];
        f4fma(acc0, a0.x, b0); f4fma(acc0, a0.y, b1); f4fma(acc0, a0.z, b2); f4fma(acc0, a0.w, b3);
        f4fma(acc1, a1.x, b0); f4fma(acc1, a1.y, b1); f4fma(acc1, a1.z, b2); f4fma(acc1, a1.w, b3);
        f4fma(acc2, a2.x, b0); f4fma(acc2, a2.y, b1); f4fma(acc2, a2.z, b2); f4fma(acc2, a2.w, b3);
        f4fma(acc3, a3.x, b0); f4fma(acc3, a3.y, b1); f4fma(acc3, a3.z, b2); f4fma(acc3, a3.w, b3);
    }
    int grow = nbase + row0;
#pragma unroll
    for (int r = 0; r < 4; ++r) {
        int rr = grow + r;
        if (rr < n) {
            float d = dis[rr];
            float4 o = (r == 0) ? acc0 : (r == 1) ? acc1 : (r == 2) ? acc2 : acc3;
            o.x *= d; o.y *= d; o.z *= d; o.w *= d;
            h4store(&h1s[(size_t)rr * 64 + col0], o);
        }
    }
}

// Layer-1 aggregation + relu/b1 + gemm2, fused (round-4 shape: one node
// per wave, 25K blocks, W2 column in 32 VGPRs via coalesced scalar
// global loads).  fp16 row = 128 B = 8 lanes x 16 B: eg = lane>>3 (8
// edge slots), fq = (lane&7)*8; one dwordx4 covers 8 edges.  v_fma_mix
// accumulate.  Shuffles all-lane; only the add is predicated.  meta =
// (rowstart,deg) in one 8-B load.  unroll 8 on the <=64 gather: up to 8
// dwordx4 in flight per wave (latency window 4->8 KB).
__global__ __launch_bounds__(256) void k_agg12(
        const __half* __restrict__ h1s, const int* __restrict__ ents,
        const int2* __restrict__ meta,
        const float* __restrict__ dis, const float* __restrict__ b1,
        const float* __restrict__ W2, __half* __restrict__ h2s, int n) {
    __shared__ float h1row[4][72];
    int wid = threadIdx.x >> 6, lane = threadIdx.x & 63;
    int v = blockIdx.x * 4 + wid;
    int vc = min(v, n - 1);            // no early return (syncthreads below)
    int2 md = meta[vc];
    int start = md.x, cnt = md.y;
    int eg = lane >> 3;
    int fq = (lane & 7) * 8;           // half-index of this lane's 8 features
    int c = lane & 31, hh = lane >> 5;
    // preload W2 column c, k-range [hh*32, hh*32+32) -> 32 VGPRs
    float w2r[32];
#pragma unroll
    for (int j = 0; j < 32; ++j)
        w2r[j] = W2[(hh * 32 + j) * 32 + c];
    float4 accA = {0.f, 0.f, 0.f, 0.f}, accB = accA;
    if (cnt > 0 && cnt <= 64) {
        int pre = ents[start + min(lane, cnt - 1)];
        int ng = cnt >> 3;
#pragma unroll 8
        for (int g = 0; g < ng; ++g) {
            unsigned s = ((unsigned)__shfl(pre, g * 8 + eg)) >> BSHIFT;
            h8acc(&h1s[(size_t)s * 64 + fq], accA, accB);
        }
        int rem = cnt & 7, j0 = cnt & ~7;
        if (rem) {
            unsigned s = ((unsigned)__shfl(pre, j0 + (eg < rem ? eg : 0))) >> BSHIFT;
            float4 a, b; h8load(&h1s[(size_t)s * 64 + fq], a, b);
            if (eg < rem) { f4add(accA, a); f4add(accB, b); }
        }
    } else if (cnt > 64) {
        int j = 0;
        for (; j + 8 <= cnt; j += 8) {
            unsigned s = ((unsigned)ents[start + j + eg]) >> BSHIFT;
            h8acc(&h1s[(size_t)s * 64 + fq], accA, accB);
        }
        int rem = cnt - j;
        if (rem) {
            unsigned s = ((unsigned)ents[start + j + (eg < rem ? eg : 0)]) >> BSHIFT;
            float4 a, b; h8load(&h1s[(size_t)s * 64 + fq], a, b);
            if (eg < rem) { f4add(accA, a); f4add(accB, b); }
        }
    }
    if (eg == 0) {                     // self loop
        h8acc(&h1s[(size_t)vc * 64 + fq], accA, accB);
    }
    f4red(accA, 8);  f4red(accB, 8);
    f4red(accA, 16); f4red(accB, 16);
    f4red(accA, 32); f4red(accB, 32);
    float d = dis[vc];
    if (eg == 0) {
        float4 bq0 = *(const float4*)&b1[fq];
        float4 bq1 = *(const float4*)&b1[fq + 4];
        float4 o0, o1;
        o0.x = fmaxf(fmaf(d, accA.x, bq0.x), 0.f);
        o0.y = fmaxf(fmaf(d, accA.y, bq0.y), 0.f);
        o0.z = fmaxf(fmaf(d, accA.z, bq0.z), 0.f);
        o0.w = fmaxf(fmaf(d, accA.w, bq0.w), 0.f);
        o1.x = fmaxf(fmaf(d, accB.x, bq1.x), 0.f);
        o1.y = fmaxf(fmaf(d, accB.y, bq1.y), 0.f);
        o1.z = fmaxf(fmaf(d, accB.z, bq1.z), 0.f);
        o1.w = fmaxf(fmaf(d, accB.w, bq1.w), 0.f);
        *(float4*)&h1row[wid][fq] = o0;
        *(float4*)&h1row[wid][fq + 4] = o1;
    }
    __syncthreads();     // orders each wave's LDS row write before its reads
    // gemm2 in-wave: lane computes h2[c] partial over its k-half
    float p = 0.f;
#pragma unroll
    for (int j = 0; j < 32; j += 4) {
        float4 hv = *(const float4*)&h1row[wid][hh * 32 + j];
        p = fmaf(hv.x, w2r[j + 0], p);
        p = fmaf(hv.y, w2r[j + 1], p);
        p = fmaf(hv.z, w2r[j + 2], p);
        p = fmaf(hv.w, w2r[j + 3], p);
    }
    p += __shfl_xor(p, 32);
    if (hh == 0 && v < n) h2s[(size_t)v * 32 + c] = __float2half(p * d);
}

// layer-2 aggregation + relu + FC head.  fp16 row = 64 B = 4 lanes x 16 B:
// eg = lane>>2 (16 edge slots), fq = (lane&3)*8 halves; one dwordx4 covers
// 16 edges per instruction.  v_fma_mix accumulate; xor-4/8/16/32 reduce;
// FC in lanes 0-3.  meta = (rowstart,deg) in one 8-B load.
__global__ void k_agg2(const __half* __restrict__ h2s, const int* __restrict__ ents,
                       const int2* __restrict__ meta,
                       const float* __restrict__ dis, const float* __restrict__ b2,
                       const float* __restrict__ Wfc, const float* __restrict__ bfc,
                       float* __restrict__ out, int n) {
    int wid = threadIdx.x >> 6, lane = threadIdx.x & 63;
    int v = blockIdx.x * 4 + wid;
    if (v >= n) return;
    int2 md = meta[v];
    int start = md.x, cnt = md.y;
    int eg = lane >> 2;
    int fq = (lane & 3) * 8;
    float4 accA = {0.f, 0.f, 0.f, 0.f}, accB = accA;
    if (cnt > 0 && cnt <= 64) {
        int pre = ents[start + min(lane, cnt - 1)];
        int ng = cnt >> 4;
#pragma unroll 4
        for (int g = 0; g < ng; ++g) {
            unsigned s = ((unsigned)__shfl(pre, g * 16 + eg)) >> BSHIFT;
            h8acc(&h2s[(size_t)s * 32 + fq], accA, accB);
        }
        int rem = cnt & 15, j0 = cnt & ~15;
        if (rem) {
            unsigned s = ((unsigned)__shfl(pre, j0 + (eg < rem ? eg : 0))) >> BSHIFT;
            float4 a, b; h8load(&h2s[(size_t)s * 32 + fq], a, b);
            if (eg < rem) { f4add(accA, a); f4add(accB, b); }
        }
    } else if (cnt > 64) {
        int j = 0;
        for (; j + 16 <= cnt; j += 16) {
            unsigned s = ((unsigned)ents[start + j + eg]) >> BSHIFT;
            h8acc(&h2s[(size_t)s * 32 + fq], accA, accB);
        }
        int rem = cnt - j;
        if (rem) {
            unsigned s = ((unsigned)ents[start + j + (eg < rem ? eg : 0)]) >> BSHIFT;
            float4 a, b; h8load(&h2s[(size_t)s * 32 + fq], a, b);
            if (eg < rem) { f4add(accA, a); f4add(accB, b); }
        }
    }
    if (eg == 0) {                     // self loop (lanes 0-3)
        h8acc(&h2s[(size_t)v * 32 + fq], accA, accB);
    }
    f4red(accA, 4);  f4red(accB, 4);
    f4red(accA, 8);  f4red(accB, 8);
    f4red(accA, 16); f4red(accB, 16);
    f4red(accA, 32); f4red(accB, 32);
    float p = 0.f;
    if (eg == 0) {
        float d = dis[v];
        float4 bq0 = *(const float4*)&b2[fq];
        float4 bq1 = *(const float4*)&b2[fq + 4];
        float4 wq0 = *(const float4*)&Wfc[fq];
        float4 wq1 = *(const float4*)&Wfc[fq + 4];
        p  = fmaxf(fmaf(d, accA.x, bq0.x), 0.f) * wq0.x;
        p += fmaxf(fmaf(d, accA.y, bq0.y), 0.f) * wq0.y;
        p += fmaxf(fmaf(d, accA.z, bq0.z), 0.f) * wq0.z;
        p += fmaxf(fmaf(d, accA.w, bq0.w), 0.f) * wq0.w;
        p += fmaxf(fmaf(d, accB.x, bq1.x), 0.f) * wq1.x;
        p += fmaxf(fmaf(d, accB.y, bq1.y), 0.f) * wq1.y;
        p += fmaxf(fmaf(d, accB.z, bq1.z), 0.f) * wq1.z;
        p += fmaxf(fmaf(d, accB.w, bq1.w), 0.f) * wq1.w;
    }
    p += __shfl_xor(p, 1); p += __shfl_xor(p, 2);
    if (lane == 0) out[v] = p + bfc[0];
}

extern "C" void kernel_launch(void* const* d_in, const int* in_sizes, int n_in,
                              void* d_out, int out_size, void* d_ws, size_t ws_size,
                              hipStream_t stream) {
    const float* x   = (const float*)d_in[0];
    const int*   ei  = (const int*)d_in[1];
    const float* W1  = (const float*)d_in[2];
    const float* b1  = (const float*)d_in[3];
    const float* W2  = (const float*)d_in[4];
    const float* b2  = (const float*)d_in[5];
    const float* Wfc = (const float*)d_in[6];
    const float* bfc = (const float*)d_in[7];
    float* out = (float*)d_out;

    const int n = in_sizes[0] / 128;       // 100000
    const int e = in_sizes[1] / 2;         // 3200000
    const int* src = ei;
    const int* dst = ei + e;

    const int nbuck = (n + BSIZE - 1) / BSIZE;           // 782
    const int m = nbuck * B1;                            // 200192
    const int echunk = (e + B1 - 1) / B1;                // 12500

    char* p = (char*)d_ws;
    size_t off = 0;
    auto carve = [&](size_t bytes) { void* r = p + off; off = (off + bytes + 255) & ~(size_t)255; return r; };
    int*   ghist   = (int*)  carve((size_t)m * 4);
    int*   ghist_s = (int*)  carve((size_t)m * 4);
    int*   part    = (int*)  carve(256 * 4);
    float* dis     = (float*)carve((size_t)n * 4);
    int2*  meta    = (int2*) carve((size_t)n * 8);
    int*   ebuf2   = (int*)  carve((size_t)e * 4);
    __half* h2s    = (__half*)carve((size_t)n * 32 * 2);
    void*  ebuf_or_h1s = carve((size_t)e * 4);           // ebuf(E*4) aliases h1s(N*64*2)
    int*    ebuf = (int*)ebuf_or_h1s;
    __half* h1s  = (__half*)ebuf_or_h1s;
    (void)ws_size;

    const int nblk_scan = (m + SCAN_CHUNK - 1) / SCAN_CHUNK;   // 196 (<=256)
    const size_t lds_buck = (size_t)nbuck * 4;

    k_hist<<<B1, 256, lds_buck, stream>>>(dst, ghist, e, echunk, nbuck);
    k_gscan1<<<nblk_scan, 256, 0, stream>>>(ghist, part, m);
    k_gscan2<<<nblk_scan, 256, 0, stream>>>(ghist, part, ghist_s, m, nblk_scan);
    k_binscatter<<<B1, 256, lds_buck, stream>>>(src, dst, ghist_s, ebuf, e, echunk, nbuck);
    k_csr<<<nbuck, 256, 0, stream>>>(ebuf, ghist_s, ebuf2, meta, dis, n, e, nbuck);
    k_gemm1<<<(n + 63) / 64, 256, 0, stream>>>(x, W1, dis, h1s, n);
    k_agg12<<<(n + 3) / 4, 256, 0, stream>>>(h1s, ebuf2, meta, dis, b1, W2, h2s, n);
    k_agg2<<<(n + 3) / 4, 256, 0, stream>>>(h2s, ebuf2, meta, dis, b2, Wfc, bfc, out, n);
}